// Round 7
// baseline (135.292 us; speedup 1.0000x reference)
//
#include <hip/hip_runtime.h>
#include <hip/hip_bf16.h>
#include <math.h>
#include <type_traits>

// Problem constants (CausalSelfAttention, GPT-2 small shape)
#define BATCH 8
#define SEQ   1024
#define NEMBD 768
#define NHEAD 12
#define HDIM  64
#define TC    (3 * NEMBD)   // 2304

typedef __attribute__((ext_vector_type(4))) float f32x4;
typedef __attribute__((ext_vector_type(8))) short s16x8;   // 8 bf16 in 4 VGPRs

__device__ __forceinline__ unsigned short f2bf(float f) {
    return __builtin_bit_cast(unsigned short, __float2bfloat16(f));
}

// async global->LDS, 16B per lane (dwordx4)
__device__ __forceinline__ void gload_lds16(const void* g, void* l) {
    __builtin_amdgcn_global_load_lds(
        (const __attribute__((address_space(1))) void*)g,
        (__attribute__((address_space(3))) void*)l, 16, 0, 0);
}

// ---------------------------------------------------------------------------
// cast fp32 -> bf16, 8 elements/thread
// ---------------------------------------------------------------------------
__global__ __launch_bounds__(256) void cast_bf16_kernel(
    const float* __restrict__ in, unsigned short* __restrict__ out, int n)
{
    const int i = (blockIdx.x * 256 + threadIdx.x) * 8;
    float4 a = *(const float4*)(in + i);
    float4 b = *(const float4*)(in + i + 4);
    s16x8 v;
    v[0] = f2bf(a.x); v[1] = f2bf(a.y); v[2] = f2bf(a.z); v[3] = f2bf(a.w);
    v[4] = f2bf(b.x); v[5] = f2bf(b.y); v[6] = f2bf(b.z); v[7] = f2bf(b.w);
    *(s16x8*)(out + i) = v;
}

// ---------------------------------------------------------------------------
// transpose + cast: w[K][N] fp32 -> wT[N][K] bf16. 32x32 LDS tiles.
// ---------------------------------------------------------------------------
__global__ __launch_bounds__(256) void transpose_cast_kernel(
    const float* __restrict__ w, unsigned short* __restrict__ wT, int K, int N)
{
    __shared__ float t[32][33];
    const int tx = threadIdx.x, ty = threadIdx.y;   // block (32,8)
    const int n0 = blockIdx.x * 32, k0 = blockIdx.y * 32;
    #pragma unroll
    for (int i = 0; i < 4; ++i)
        t[ty + i * 8][tx] = w[(size_t)(k0 + ty + i * 8) * N + n0 + tx];
    __syncthreads();
    #pragma unroll
    for (int i = 0; i < 4; ++i)
        wT[(size_t)(n0 + ty + i * 8) * K + k0 + tx] = f2bf(t[tx][ty + i * 8]);
}

// ---------------------------------------------------------------------------
// Deep-pipelined bf16 MFMA GEMM: C[M,N] = A[M,K] @ Bt[N,K]^T + bias.
// BK=32, 4 LDS K-tile buffers, 2-tile-deep global_load_lds prefetch with
// COUNTED vmcnt (never drained to 0 in steady state), ONE raw s_barrier per
// K-tile (no compiler vmcnt-drain).  Fragment ds_read_b128 are bank-balanced
// via chunk XOR swizzle (chunk ^= (row>>1)&3), applied on the global SOURCE
// address at staging (rule 21: gload_lds writes LDS linearly) and on the
// LDS read address.
// Wave grid WM x WN; per-wave output (MF*16) x (NF*16).
// OUTK=0: fp32 C + bias.  OUTK=1: QKV epilogue (Q,K [b,h,t,d]; Vt [b,h,d,t]).
//
// Pipeline hazard analysis (buffers cycle mod 4):
//   iter t: reads buf[t&3]; stages tile t+2 into buf[(t+2)&3].
//   buf[(t+2)&3] was last ds_read at iter t-2; those reads completed before
//   t-2's MFMAs (auto lgkmcnt), hence before t-2's barrier < t-1's barrier
//   < this stage issue.  Tile t+1's staging (issued iter t-1) is completed
//   by this iter's vmcnt(4) before the barrier; every wave then agrees
//   buf[(t+1)&3] is valid when iter t+1 reads it.
// ---------------------------------------------------------------------------
template <int BM, int BN, int WM, int WN, int OUTK>
__global__ __launch_bounds__(64 * WM * WN, 2) void gemm_pipe_kernel(
    const unsigned short* __restrict__ A,   // [M][K] bf16
    const unsigned short* __restrict__ Bt,  // [N][K] bf16 (= B^T)
    const float* __restrict__ bias,         // [N] fp32
    float* __restrict__ C,                  // OUTK==0
    unsigned short* __restrict__ Qb,        // OUTK==1
    unsigned short* __restrict__ Kb,
    unsigned short* __restrict__ Vtb,
    int M, int N, int K, int nbn)
{
    constexpr int THREADS = 64 * WM * WN;
    constexpr int MF = BM / (16 * WM);
    constexpr int NF = BN / (16 * WN);
    constexpr int BUFB = (BM + BN) * 64;          // bytes per K-tile buffer
    static_assert(THREADS == 2 * BM && THREADS == 2 * BN, "staging map");
    __shared__ __align__(16) char smem[4 * BUFB];

    const int tid  = threadIdx.x;
    const int w    = tid >> 6, lane = tid & 63;
    const int lr   = lane & 15, lg = lane >> 4;
    const int wr   = w / WN,  wc  = w % WN;

    // XCD-bijective block swizzle (gridDim.x % 8 == 0 for all our launches)
    const int swz = (blockIdx.x & 7) * (gridDim.x >> 3) + (blockIdx.x >> 3);
    const int bm = (swz / nbn) * BM, bn = (swz % nbn) * BN;

    const int NT = K >> 5;                        // K / 32

    f32x4 acc[MF][NF];
    #pragma unroll
    for (int m = 0; m < MF; ++m)
        #pragma unroll
        for (int n = 0; n < NF; ++n) acc[m][n] = (f32x4){0.f, 0.f, 0.f, 0.f};

    auto stage = [&](int t) {
        const int k0 = t << 5;
        char* base = smem + (t & 3) * BUFB;
        #pragma unroll
        for (int i = 0; i < 2; ++i) {             // A half-tiles
            const int row = i * (BM / 2) + (tid >> 2);
            const int gc  = (tid & 3) ^ ((row >> 1) & 3);   // inverse swizzle
            gload_lds16(A + (size_t)(bm + row) * K + k0 + gc * 8,
                        base + i * (BM / 2) * 64 + tid * 16);
        }
        #pragma unroll
        for (int i = 0; i < 2; ++i) {             // B half-tiles
            const int row = i * (BN / 2) + (tid >> 2);
            const int gc  = (tid & 3) ^ ((row >> 1) & 3);
            gload_lds16(Bt + (size_t)(bn + row) * K + k0 + gc * 8,
                        base + BM * 64 + i * (BN / 2) * 64 + tid * 16);
        }
    };

    // prologue: 2 tiles in flight, wait only for tile 0 (vmcnt 4 = tile 1)
    stage(0);
    stage(1);
    asm volatile("s_waitcnt vmcnt(4)" ::: "memory");
    __builtin_amdgcn_sched_barrier(0);
    __builtin_amdgcn_s_barrier();
    __builtin_amdgcn_sched_barrier(0);

    for (int t = 0; t < NT; ++t) {
        const char* buf = smem + (t & 3) * BUFB;
        if (t + 2 < NT) stage(t + 2);

        s16x8 af[MF], bf[NF];
        #pragma unroll
        for (int m = 0; m < MF; ++m) {
            const int ar = wr * (MF * 16) + m * 16 + lr;
            af[m] = *(const s16x8*)(buf + ar * 64 + ((lg ^ ((ar >> 1) & 3)) * 16));
        }
        #pragma unroll
        for (int n = 0; n < NF; ++n) {
            const int br = wc * (NF * 16) + n * 16 + lr;
            bf[n] = *(const s16x8*)(buf + BM * 64 + br * 64
                                        + ((lg ^ ((br >> 1) & 3)) * 16));
        }

        __builtin_amdgcn_s_setprio(1);
        #pragma unroll
        for (int m = 0; m < MF; ++m)
            #pragma unroll
            for (int n = 0; n < NF; ++n)
                acc[m][n] = __builtin_amdgcn_mfma_f32_16x16x32_bf16(
                    af[m], bf[n], acc[m][n], 0, 0, 0);
        __builtin_amdgcn_s_setprio(0);

        if (t + 2 < NT) asm volatile("s_waitcnt vmcnt(4)" ::: "memory");
        else            asm volatile("s_waitcnt vmcnt(0)" ::: "memory");
        __builtin_amdgcn_sched_barrier(0);
        __builtin_amdgcn_s_barrier();
        __builtin_amdgcn_sched_barrier(0);
    }

    if constexpr (OUTK == 0) {
        #pragma unroll
        for (int n = 0; n < NF; ++n) {
            const int col = bn + wc * (NF * 16) + n * 16 + lr;
            const float bv = bias[col];
            #pragma unroll
            for (int m = 0; m < MF; ++m) {
                const int row0 = bm + wr * (MF * 16) + m * 16 + lg * 4;
                #pragma unroll
                for (int r = 0; r < 4; ++r)
                    C[(size_t)(row0 + r) * N + col] = acc[m][n][r] + bv;
            }
        }
    } else {
        // QKV epilogue: region uniform per block (768 % BN-tile grid holds)
        const int region = bn / NEMBD;            // 0=Q, 1=K, 2=V
        #pragma unroll
        for (int n = 0; n < NF; ++n) {
            const int col = bn + wc * (NF * 16) + n * 16 + lr;
            const int hd  = col - region * NEMBD;
            const int hh  = hd >> 6, d = hd & 63;
            const float bv = bias[col];
            #pragma unroll
            for (int m = 0; m < MF; ++m) {
                const int row0 = bm + wr * (MF * 16) + m * 16 + lg * 4;
                const int bb = row0 >> 10, t0 = row0 & 1023;  // no 1024-crossing
                if (region == 2) {
                    ushort4 pk;
                    pk.x = f2bf(acc[m][n][0] + bv);
                    pk.y = f2bf(acc[m][n][1] + bv);
                    pk.z = f2bf(acc[m][n][2] + bv);
                    pk.w = f2bf(acc[m][n][3] + bv);
                    *(ushort4*)&Vtb[(((size_t)bb * NHEAD + hh) * HDIM + d) * SEQ + t0] = pk;
                } else {
                    unsigned short* dst = (region == 0) ? Qb : Kb;
                    const size_t tb = ((size_t)bb * NHEAD + hh) * SEQ;
                    #pragma unroll
                    for (int r = 0; r < 4; ++r)
                        dst[(tb + t0 + r) * HDIM + d] = f2bf(acc[m][n][r] + bv);
                }
            }
        }
    }
}

// ---------------------------------------------------------------------------
// Flash attention, bf16 MFMA, operand-swapped (S^T) softmax.
// 1-D grid 1536 = 8 XCD-classes x 12 bh-groups x 16 q-tiles. All 16 q-tiles
// of one (b,h) share one XCD-class -> K/V re-reads are L2 hits. qt descends
// within each class (long blocks first).
// Block 256 thr = 4 waves; wave w owns 16 q-rows [qt*64+w*16, +16).
// ---------------------------------------------------------------------------
__global__ __launch_bounds__(256) void attn_mfma_kernel(
    const unsigned short* __restrict__ Qb,
    const unsigned short* __restrict__ Kb,
    const unsigned short* __restrict__ Vtb,
    unsigned short* __restrict__ y)
{
    const int bid = blockIdx.x;
    const int xcd = bid & 7;
    const int grp = bid >> 3;             // 0..191
    const int qt  = 15 - (grp & 15);      // long blocks first within class
    const int bh  = xcd + 8 * (grp >> 4); // 0..95
    const int b   = bh / NHEAD, h = bh % NHEAD;

    const int tid  = threadIdx.x;
    const int w    = tid >> 6;
    const int lane = tid & 63;
    const int lr   = lane & 15;
    const int lg   = lane >> 4;

    __shared__ __align__(16) unsigned short Ks[64 * 64];    // swizzled [k][d]
    __shared__ __align__(16) unsigned short Vs[64 * 64];    // swizzled [d][t]
    __shared__ __align__(16) unsigned short Ps[4][16][72];  // per-wave P [q][k]

    const unsigned short* Qg = Qb  + ((size_t)bh * SEQ + qt * 64 + w * 16) * HDIM;
    const unsigned short* Kg = Kb  + (size_t)bh * SEQ * HDIM;
    const unsigned short* Vg = Vtb + (size_t)bh * HDIM * SEQ;

    // Q B-frags: col q = lr, kdim d = kc*32 + lg*8 + j
    s16x8 qf[2];
    #pragma unroll
    for (int kc = 0; kc < 2; ++kc)
        qf[kc] = *(const s16x8*)(Qg + (size_t)lr * HDIM + kc * 32 + lg * 8);

    f32x4 acc[4];                         // O^T frags: row d = df*16+lg*4+r, col q = lr
    #pragma unroll
    for (int df = 0; df < 4; ++df) acc[df] = (f32x4){0.f, 0.f, 0.f, 0.f};
    float mrow = -INFINITY, lrow = 0.f;

    // staging maps: thread -> row tid>>2, 16-elem chunk (tid&3)
    const int sr = tid >> 2;
    const int sc = (tid & 3) * 16;
    const unsigned short* Kgr = Kg + (size_t)sr * HDIM + sc;
    const unsigned short* Vgr = Vg + (size_t)sr * SEQ  + sc;
    const int swz0 = sr * 128 + ((sc * 2)      ^ ((sr & 7) << 4));
    const int swz1 = sr * 128 + ((sc * 2 + 16) ^ ((sr & 7) << 4));
    const int xorv = (lr & 7) << 4;       // read-side swizzle

    const int NT   = qt + 1;
    const int qrow = qt * 64 + w * 16 + lr;

    // prologue: tile-0 loads into regs
    s16x8 krA = *(const s16x8*)(Kgr);
    s16x8 krB = *(const s16x8*)(Kgr + 8);
    s16x8 vrA = *(const s16x8*)(Vgr);
    s16x8 vrB = *(const s16x8*)(Vgr + 8);

    for (int kt = 0; kt < NT; ++kt) {
        __syncthreads();                  // LDS consumed
        *(s16x8*)((char*)Ks + swz0) = krA;
        *(s16x8*)((char*)Ks + swz1) = krB;
        *(s16x8*)((char*)Vs + swz0) = vrA;
        *(s16x8*)((char*)Vs + swz1) = vrB;
        __syncthreads();                  // tile visible
        if (kt + 1 < NT) {                // T14: issue next tile's loads now
            krA = *(const s16x8*)(Kgr + (size_t)(kt + 1) * 64 * HDIM);
            krB = *(const s16x8*)(Kgr + (size_t)(kt + 1) * 64 * HDIM + 8);
            vrA = *(const s16x8*)(Vgr + (kt + 1) * 64);
            vrB = *(const s16x8*)(Vgr + (kt + 1) * 64 + 8);
        }

        // ---- S^T = K Q : 8 MFMA (A = K frags from swizzled LDS, B = Q) ----
        f32x4 sf[4];
        __builtin_amdgcn_s_setprio(1);
        #pragma unroll
        for (int s = 0; s < 4; ++s) {
            const int rb = (s * 16 + lr) * 128;
            s16x8 a0 = *(const s16x8*)((const char*)Ks + rb + ((lg * 16) ^ xorv));
            s16x8 a1 = *(const s16x8*)((const char*)Ks + rb + ((64 + lg * 16) ^ xorv));
            sf[s] = __builtin_amdgcn_mfma_f32_16x16x32_bf16(
                a0, qf[0], (f32x4){0.f, 0.f, 0.f, 0.f}, 0, 0, 0);
            sf[s] = __builtin_amdgcn_mfma_f32_16x16x32_bf16(a1, qf[1], sf[s], 0, 0, 0);
        }
        __builtin_amdgcn_s_setprio(0);

        // ---- scale + causal mask: key = kt*64+s*16+lg*4+r, q = qrow ----
        float sv[4][4];
        #pragma unroll
        for (int s = 0; s < 4; ++s)
            #pragma unroll
            for (int r = 0; r < 4; ++r)
                sv[s][r] = sf[s][r] * 0.125f;
        if (kt == NT - 1) {
            const int kbase = kt * 64;
            #pragma unroll
            for (int s = 0; s < 4; ++s)
                #pragma unroll
                for (int r = 0; r < 4; ++r)
                    if (kbase + s * 16 + lg * 4 + r > qrow)
                        sv[s][r] = -INFINITY;
        }

        // ---- online softmax: in-lane tree + 2 shfl rounds (lane bits 4,5) ----
        float mx4[4];
        #pragma unroll
        for (int s = 0; s < 4; ++s)
            mx4[s] = fmaxf(fmaxf(sv[s][0], sv[s][1]), fmaxf(sv[s][2], sv[s][3]));
        float mx = fmaxf(fmaxf(mx4[0], mx4[1]), fmaxf(mx4[2], mx4[3]));
        mx = fmaxf(mx, __shfl_xor(mx, 16, 64));
        mx = fmaxf(mx, __shfl_xor(mx, 32, 64));
        const float mnew = fmaxf(mrow, mx);
        const float al   = __expf(mrow - mnew);   // mrow=-inf first tile -> 0
        mrow = mnew;

        float rsum = 0.f;
        #pragma unroll
        for (int s = 0; s < 4; ++s) {
            float p0 = __expf(sv[s][0] - mnew);
            float p1 = __expf(sv[s][1] - mnew);
            float p2 = __expf(sv[s][2] - mnew);
            float p3 = __expf(sv[s][3] - mnew);
            rsum += (p0 + p1) + (p2 + p3);
            ushort4 pk;
            pk.x = f2bf(p0); pk.y = f2bf(p1); pk.z = f2bf(p2); pk.w = f2bf(p3);
            *(ushort4*)&Ps[w][lr][s * 16 + lg * 4] = pk;   // k-contiguous
        }
        rsum += __shfl_xor(rsum, 16, 64);
        rsum += __shfl_xor(rsum, 32, 64);
        lrow = lrow * al + rsum;

        #pragma unroll
        for (int df = 0; df < 4; ++df) acc[df] *= al;      // lane-local rescale

        asm volatile("s_waitcnt lgkmcnt(0)" ::: "memory");
        __builtin_amdgcn_sched_barrier(0);
        s16x8 pa[2];
        #pragma unroll
        for (int kc = 0; kc < 2; ++kc)
            pa[kc] = *(const s16x8*)&Ps[w][lr][kc * 32 + lg * 8];

        // ---- O^T += V^T P^T : 8 MFMA (A = V^T frags from swizzled LDS) ----
        __builtin_amdgcn_s_setprio(1);
        #pragma unroll
        for (int df = 0; df < 4; ++df) {
            const int rb = (df * 16 + lr) * 128;
            s16x8 va0 = *(const s16x8*)((const char*)Vs + rb + ((lg * 16) ^ xorv));
            s16x8 va1 = *(const s16x8*)((const char*)Vs + rb + ((64 + lg * 16) ^ xorv));
            acc[df] = __builtin_amdgcn_mfma_f32_16x16x32_bf16(va0, pa[0], acc[df], 0, 0, 0);
            acc[df] = __builtin_amdgcn_mfma_f32_16x16x32_bf16(va1, pa[1], acc[df], 0, 0, 0);
        }
        __builtin_amdgcn_s_setprio(0);
    }

    // ---- epilogue: lane-local 1/l, write y (8B packed, d-contiguous) ----
    const float inv = 1.f / lrow;
    const int t = qt * 64 + w * 16 + lr;
    unsigned short* yp = y + ((size_t)(b * SEQ) + t) * NEMBD + h * HDIM;
    #pragma unroll
    for (int df = 0; df < 4; ++df) {
        ushort4 pk;
        pk.x = f2bf(acc[df][0] * inv);
        pk.y = f2bf(acc[df][1] * inv);
        pk.z = f2bf(acc[df][2] * inv);
        pk.w = f2bf(acc[df][3] * inv);
        *(ushort4*)(yp + df * 16 + lg * 4) = pk;
    }
}

// ---------------------------------------------------------------------------
extern "C" void kernel_launch(void* const* d_in, const int* in_sizes, int n_in,
                              void* d_out, int out_size, void* d_ws, size_t ws_size,
                              hipStream_t stream)
{
    const float* x      = (const float*)d_in[0];
    const float* w_attn = (const float*)d_in[1];
    const float* b_attn = (const float*)d_in[2];
    const float* w_proj = (const float*)d_in[3];
    const float* b_proj = (const float*)d_in[4];
    float* out = (float*)d_out;

    const int M = BATCH * SEQ;                       // 8192
    const size_t NQKV = (size_t)M * NEMBD;           // 6.29M elements

    unsigned short* xb  = (unsigned short*)d_ws;           // [M][768]
    unsigned short* waT = xb  + NQKV;                      // [2304][768]
    unsigned short* wpT = waT + (size_t)TC * NEMBD;        // [768][768]
    unsigned short* Qb  = wpT + (size_t)NEMBD * NEMBD;     // [B][H][T][D]
    unsigned short* Kb  = Qb  + NQKV;                      // [B][H][T][D]
    unsigned short* Vtb = Kb  + NQKV;                      // [B][H][D][T]
    unsigned short* yb  = Vtb + NQKV;                      // [M][768]

    // 0) bf16 prep
    cast_bf16_kernel<<<(M * NEMBD) / 2048, 256, 0, stream>>>(x, xb, M * NEMBD);
    transpose_cast_kernel<<<dim3(TC / 32, NEMBD / 32), dim3(32, 8), 0, stream>>>(
        w_attn, waT, NEMBD, TC);
    transpose_cast_kernel<<<dim3(NEMBD / 32, NEMBD / 32), dim3(32, 8), 0, stream>>>(
        w_proj, wpT, NEMBD, NEMBD);

    // 1) fused QKV GEMM (256^2 tile, 8 waves) -> Q, K, V^T buffers (bf16)
    gemm_pipe_kernel<256, 256, 2, 4, 1><<<(TC / 256) * (M / 256), 512, 0, stream>>>(
        xb, waT, b_attn, nullptr, Qb, Kb, Vtb, M, TC, NEMBD, TC / 256);

    // 2) operand-swapped MFMA attention -> yb bf16 [B,T,C]
    attn_mfma_kernel<<<16 * NHEAD * BATCH, 256, 0, stream>>>(Qb, Kb, Vtb, yb);

    // 3) out(fp32) = yb @ wpT^T + b_proj (128^2 tile, 4 waves)
    gemm_pipe_kernel<128, 128, 2, 2, 0><<<(NEMBD / 128) * (M / 128), 256, 0, stream>>>(
        yb, wpT, b_proj, out, nullptr, nullptr, nullptr, M, NEMBD, NEMBD, NEMBD / 128);
}

// Round 8
// 129.658 us; speedup vs baseline: 1.0435x; 1.0435x over previous
//
#include <hip/hip_runtime.h>
#include <hip/hip_bf16.h>
#include <math.h>
#include <type_traits>

// Problem constants (CausalSelfAttention, GPT-2 small shape)
#define BATCH 8
#define SEQ   1024
#define NEMBD 768
#define NHEAD 12
#define HDIM  64
#define TC    (3 * NEMBD)   // 2304

typedef __attribute__((ext_vector_type(4))) float f32x4;
typedef __attribute__((ext_vector_type(8))) short s16x8;   // 8 bf16 in 4 VGPRs

__device__ __forceinline__ unsigned short f2bf(float f) {
    return __builtin_bit_cast(unsigned short, __float2bfloat16(f));
}

// async global->LDS, 16B per lane (dwordx4)
__device__ __forceinline__ void gload_lds16(const void* g, void* l) {
    __builtin_amdgcn_global_load_lds(
        (const __attribute__((address_space(1))) void*)g,
        (__attribute__((address_space(3))) void*)l, 16, 0, 0);
}

// ---------------------------------------------------------------------------
// cast fp32 -> bf16, 8 elements/thread
// ---------------------------------------------------------------------------
__global__ __launch_bounds__(256) void cast_bf16_kernel(
    const float* __restrict__ in, unsigned short* __restrict__ out, int n)
{
    const int i = (blockIdx.x * 256 + threadIdx.x) * 8;
    float4 a = *(const float4*)(in + i);
    float4 b = *(const float4*)(in + i + 4);
    s16x8 v;
    v[0] = f2bf(a.x); v[1] = f2bf(a.y); v[2] = f2bf(a.z); v[3] = f2bf(a.w);
    v[4] = f2bf(b.x); v[5] = f2bf(b.y); v[6] = f2bf(b.z); v[7] = f2bf(b.w);
    *(s16x8*)(out + i) = v;
}

// ---------------------------------------------------------------------------
// transpose + cast: w[K][N] fp32 -> wT[N][K] bf16. 32x32 LDS tiles.
// ---------------------------------------------------------------------------
__global__ __launch_bounds__(256) void transpose_cast_kernel(
    const float* __restrict__ w, unsigned short* __restrict__ wT, int K, int N)
{
    __shared__ float t[32][33];
    const int tx = threadIdx.x, ty = threadIdx.y;   // block (32,8)
    const int n0 = blockIdx.x * 32, k0 = blockIdx.y * 32;
    #pragma unroll
    for (int i = 0; i < 4; ++i)
        t[ty + i * 8][tx] = w[(size_t)(k0 + ty + i * 8) * N + n0 + tx];
    __syncthreads();
    #pragma unroll
    for (int i = 0; i < 4; ++i)
        wT[(size_t)(n0 + ty + i * 8) * K + k0 + tx] = f2bf(t[tx][ty + i * 8]);
}

// ---------------------------------------------------------------------------
// bf16 MFMA GEMM (m97 structure + chunk-XOR bank swizzle), fp32 out + bias:
// C[M,N] = A[M,K] @ Bt[N,K]^T + bias.  128x128 tile, BK=32, 4 waves.
// Swizzle (validated r7, conflicts->0): LDS[row][c] holds global chunk
// c ^ ((row>>1)&3); staging applies inverse on the global SOURCE column
// (gload_lds writes LDS linearly, rule 21), reads XOR the chunk index.
// ---------------------------------------------------------------------------
__global__ __launch_bounds__(256) void gemm_mfma_f32_kernel(
    const unsigned short* __restrict__ A,
    const unsigned short* __restrict__ Bt,
    const float* __restrict__ bias,
    float* __restrict__ C,
    int M, int N, int K)
{
    __shared__ __align__(16) unsigned short As[128 * 32];
    __shared__ __align__(16) unsigned short Bs[128 * 32];

    const int tid  = threadIdx.x;
    const int w    = tid >> 6, lane = tid & 63;
    const int lr   = lane & 15, lg = lane >> 4;
    const int wr   = w >> 1, wc = w & 1;
    const int bm   = blockIdx.y * 128, bn = blockIdx.x * 128;

    const int srow = tid >> 2;                          // row within 64-row half
    const int gc   = (tid & 3) ^ ((srow >> 1) & 3);     // inverse-swizzled chunk
    const unsigned short* Ag = A  + (size_t)(bm + srow) * K + gc * 8;
    const unsigned short* Bg = Bt + (size_t)(bn + srow) * K + gc * 8;
    unsigned short* Al = As + tid * 8;
    unsigned short* Bl = Bs + tid * 8;
    const size_t half = (size_t)64 * K;

    f32x4 acc[4][4];
    #pragma unroll
    for (int m = 0; m < 4; ++m)
        #pragma unroll
        for (int n = 0; n < 4; ++n) acc[m][n] = (f32x4){0.f, 0.f, 0.f, 0.f};

    for (int k0 = 0; k0 < K; k0 += 32) {
        __syncthreads();
        gload_lds16(Ag + k0,        Al);
        gload_lds16(Ag + k0 + half, Al + 2048);
        gload_lds16(Bg + k0,        Bl);
        gload_lds16(Bg + k0 + half, Bl + 2048);
        __syncthreads();

        s16x8 af[4], bfr[4];
        #pragma unroll
        for (int m = 0; m < 4; ++m) {
            const int ar = wr * 64 + m * 16 + lr;
            af[m] = *(const s16x8*)&As[ar * 32 + ((lg ^ ((ar >> 1) & 3)) * 8)];
        }
        #pragma unroll
        for (int n = 0; n < 4; ++n) {
            const int br = wc * 64 + n * 16 + lr;
            bfr[n] = *(const s16x8*)&Bs[br * 32 + ((lg ^ ((br >> 1) & 3)) * 8)];
        }
        #pragma unroll
        for (int m = 0; m < 4; ++m)
            #pragma unroll
            for (int n = 0; n < 4; ++n)
                acc[m][n] = __builtin_amdgcn_mfma_f32_16x16x32_bf16(
                    af[m], bfr[n], acc[m][n], 0, 0, 0);
    }

    #pragma unroll
    for (int n = 0; n < 4; ++n) {
        const int col = bn + wc * 64 + n * 16 + lr;
        const float bv = bias[col];
        #pragma unroll
        for (int m = 0; m < 4; ++m) {
            const int row0 = bm + wr * 64 + m * 16 + lg * 4;
            #pragma unroll
            for (int r = 0; r < 4; ++r)
                C[(size_t)(row0 + r) * N + col] = acc[m][n][r] + bv;
        }
    }
}

// ---------------------------------------------------------------------------
// Same GEMM core + coalesced QKV epilogue.
// Per-wave output tile = 64 t-rows x 64 cols, and cols = one full head
// (BN=128 = 2 heads, wc selects the head).  Epilogue retiles the wave's
// 64x64 fragment set through a per-wave LDS buffer [64][72] (bank-free:
// read banks 4*(row+chunk) mod 32 -> 2 lanes/bank) and stores full 128B
// rows with 16B/lane global_store_dwordx4:
//   region Q/K: S[t][d], rows -> Qb/Kb[b,h,t0+t][0..63]
//   region V  : S[d][t], rows -> Vtb[b,h,d][t0..t0+63]
// ---------------------------------------------------------------------------
__global__ __launch_bounds__(256) void gemm_mfma_qkv_kernel(
    const unsigned short* __restrict__ A,   // xb [M][768]
    const unsigned short* __restrict__ Bt,  // waT [2304][768]
    const float* __restrict__ bias,         // b_attn [2304]
    unsigned short* __restrict__ Qb,
    unsigned short* __restrict__ Kb,
    unsigned short* __restrict__ Vtb,
    int M, int K)
{
    __shared__ __align__(16) unsigned short As[128 * 32];
    __shared__ __align__(16) unsigned short Bs[128 * 32];
    __shared__ __align__(16) unsigned short Ep[4][64][72];   // per-wave retile

    const int tid  = threadIdx.x;
    const int w    = tid >> 6, lane = tid & 63;
    const int lr   = lane & 15, lg = lane >> 4;
    const int wr   = w >> 1, wc = w & 1;
    const int bm   = blockIdx.y * 128, bn = blockIdx.x * 128;

    const int srow = tid >> 2;
    const int gc   = (tid & 3) ^ ((srow >> 1) & 3);
    const unsigned short* Ag = A  + (size_t)(bm + srow) * K + gc * 8;
    const unsigned short* Bg = Bt + (size_t)(bn + srow) * K + gc * 8;
    unsigned short* Al = As + tid * 8;
    unsigned short* Bl = Bs + tid * 8;
    const size_t half = (size_t)64 * K;

    f32x4 acc[4][4];
    #pragma unroll
    for (int m = 0; m < 4; ++m)
        #pragma unroll
        for (int n = 0; n < 4; ++n) acc[m][n] = (f32x4){0.f, 0.f, 0.f, 0.f};

    for (int k0 = 0; k0 < K; k0 += 32) {
        __syncthreads();
        gload_lds16(Ag + k0,        Al);
        gload_lds16(Ag + k0 + half, Al + 2048);
        gload_lds16(Bg + k0,        Bl);
        gload_lds16(Bg + k0 + half, Bl + 2048);
        __syncthreads();

        s16x8 af[4], bfr[4];
        #pragma unroll
        for (int m = 0; m < 4; ++m) {
            const int ar = wr * 64 + m * 16 + lr;
            af[m] = *(const s16x8*)&As[ar * 32 + ((lg ^ ((ar >> 1) & 3)) * 8)];
        }
        #pragma unroll
        for (int n = 0; n < 4; ++n) {
            const int br = wc * 64 + n * 16 + lr;
            bfr[n] = *(const s16x8*)&Bs[br * 32 + ((lg ^ ((br >> 1) & 3)) * 8)];
        }
        #pragma unroll
        for (int m = 0; m < 4; ++m)
            #pragma unroll
            for (int n = 0; n < 4; ++n)
                acc[m][n] = __builtin_amdgcn_mfma_f32_16x16x32_bf16(
                    af[m], bfr[n], acc[m][n], 0, 0, 0);
    }

    // ---- coalesced epilogue (per-wave private Ep slice; DS pipe in-order) ----
    const int region = bn / NEMBD;                 // 0=Q, 1=K, 2=V
    const int hh = ((bn % NEMBD) >> 6) + wc;       // head 0..11
    const int row0 = bm + wr * 64;                 // 64-aligned, no 1024-crossing
    const int bb = row0 >> 10, t0 = row0 & 1023;

    float bvn[4];
    #pragma unroll
    for (int n = 0; n < 4; ++n) bvn[n] = bias[bn + wc * 64 + n * 16 + lr];

    if (region == 2) {
        #pragma unroll
        for (int m = 0; m < 4; ++m)
            #pragma unroll
            for (int n = 0; n < 4; ++n)
                #pragma unroll
                for (int r = 0; r < 4; ++r)
                    Ep[w][n * 16 + lr][m * 16 + lg * 4 + r] =
                        f2bf(acc[m][n][r] + bvn[n]);           // S[d][t]
    } else {
        #pragma unroll
        for (int m = 0; m < 4; ++m)
            #pragma unroll
            for (int n = 0; n < 4; ++n)
                #pragma unroll
                for (int r = 0; r < 4; ++r)
                    Ep[w][m * 16 + lg * 4 + r][n * 16 + lr] =
                        f2bf(acc[m][n][r] + bvn[n]);           // S[t][d]
    }

    const int rr0 = lane >> 3;       // row sub-index 0..7
    const int cc  = lane & 7;        // 16B chunk 0..7
    if (region == 2) {
        unsigned short* dst = Vtb + (((size_t)bb * NHEAD + hh) * HDIM) * SEQ + t0;
        #pragma unroll
        for (int it = 0; it < 8; ++it) {
            const int d = it * 8 + rr0;
            s16x8 v = *(const s16x8*)&Ep[w][d][cc * 8];
            *(s16x8*)(dst + (size_t)d * SEQ + cc * 8) = v;
        }
    } else {
        unsigned short* dst = (region == 0 ? Qb : Kb)
                            + ((size_t)bb * NHEAD + hh) * SEQ * HDIM;
        #pragma unroll
        for (int it = 0; it < 8; ++it) {
            const int t = it * 8 + rr0;
            s16x8 v = *(const s16x8*)&Ep[w][t][cc * 8];
            *(s16x8*)(dst + (size_t)(t0 + t) * HDIM + cc * 8) = v;
        }
    }
}

// ---------------------------------------------------------------------------
// Flash attention, bf16 MFMA, operand-swapped (S^T) softmax.
// 1-D grid 1536 = 8 XCD-classes x 12 bh-groups x 16 q-tiles (unchanged).
// ---------------------------------------------------------------------------
__global__ __launch_bounds__(256) void attn_mfma_kernel(
    const unsigned short* __restrict__ Qb,
    const unsigned short* __restrict__ Kb,
    const unsigned short* __restrict__ Vtb,
    unsigned short* __restrict__ y)
{
    const int bid = blockIdx.x;
    const int xcd = bid & 7;
    const int grp = bid >> 3;             // 0..191
    const int qt  = 15 - (grp & 15);      // long blocks first within class
    const int bh  = xcd + 8 * (grp >> 4); // 0..95
    const int b   = bh / NHEAD, h = bh % NHEAD;

    const int tid  = threadIdx.x;
    const int w    = tid >> 6;
    const int lane = tid & 63;
    const int lr   = lane & 15;
    const int lg   = lane >> 4;

    __shared__ __align__(16) unsigned short Ks[64 * 64];    // swizzled [k][d]
    __shared__ __align__(16) unsigned short Vs[64 * 64];    // swizzled [d][t]
    __shared__ __align__(16) unsigned short Ps[4][16][72];  // per-wave P [q][k]

    const unsigned short* Qg = Qb  + ((size_t)bh * SEQ + qt * 64 + w * 16) * HDIM;
    const unsigned short* Kg = Kb  + (size_t)bh * SEQ * HDIM;
    const unsigned short* Vg = Vtb + (size_t)bh * HDIM * SEQ;

    // Q B-frags: col q = lr, kdim d = kc*32 + lg*8 + j
    s16x8 qf[2];
    #pragma unroll
    for (int kc = 0; kc < 2; ++kc)
        qf[kc] = *(const s16x8*)(Qg + (size_t)lr * HDIM + kc * 32 + lg * 8);

    f32x4 acc[4];                         // O^T frags: row d = df*16+lg*4+r, col q = lr
    #pragma unroll
    for (int df = 0; df < 4; ++df) acc[df] = (f32x4){0.f, 0.f, 0.f, 0.f};
    float mrow = -INFINITY, lrow = 0.f;

    // staging maps: thread -> row tid>>2, 16-elem chunk (tid&3)
    const int sr = tid >> 2;
    const int sc = (tid & 3) * 16;
    const unsigned short* Kgr = Kg + (size_t)sr * HDIM + sc;
    const unsigned short* Vgr = Vg + (size_t)sr * SEQ  + sc;
    const int swz0 = sr * 128 + ((sc * 2)      ^ ((sr & 7) << 4));
    const int swz1 = sr * 128 + ((sc * 2 + 16) ^ ((sr & 7) << 4));
    const int xorv = (lr & 7) << 4;       // read-side swizzle

    const int NT   = qt + 1;
    const int qrow = qt * 64 + w * 16 + lr;

    // prologue: tile-0 loads into regs
    s16x8 krA = *(const s16x8*)(Kgr);
    s16x8 krB = *(const s16x8*)(Kgr + 8);
    s16x8 vrA = *(const s16x8*)(Vgr);
    s16x8 vrB = *(const s16x8*)(Vgr + 8);

    for (int kt = 0; kt < NT; ++kt) {
        __syncthreads();                  // LDS consumed
        *(s16x8*)((char*)Ks + swz0) = krA;
        *(s16x8*)((char*)Ks + swz1) = krB;
        *(s16x8*)((char*)Vs + swz0) = vrA;
        *(s16x8*)((char*)Vs + swz1) = vrB;
        __syncthreads();                  // tile visible
        if (kt + 1 < NT) {                // T14: issue next tile's loads now
            krA = *(const s16x8*)(Kgr + (size_t)(kt + 1) * 64 * HDIM);
            krB = *(const s16x8*)(Kgr + (size_t)(kt + 1) * 64 * HDIM + 8);
            vrA = *(const s16x8*)(Vgr + (kt + 1) * 64);
            vrB = *(const s16x8*)(Vgr + (kt + 1) * 64 + 8);
        }

        // ---- S^T = K Q : 8 MFMA (A = K frags from swizzled LDS, B = Q) ----
        f32x4 sf[4];
        __builtin_amdgcn_s_setprio(1);
        #pragma unroll
        for (int s = 0; s < 4; ++s) {
            const int rb = (s * 16 + lr) * 128;
            s16x8 a0 = *(const s16x8*)((const char*)Ks + rb + ((lg * 16) ^ xorv));
            s16x8 a1 = *(const s16x8*)((const char*)Ks + rb + ((64 + lg * 16) ^ xorv));
            sf[s] = __builtin_amdgcn_mfma_f32_16x16x32_bf16(
                a0, qf[0], (f32x4){0.f, 0.f, 0.f, 0.f}, 0, 0, 0);
            sf[s] = __builtin_amdgcn_mfma_f32_16x16x32_bf16(a1, qf[1], sf[s], 0, 0, 0);
        }
        __builtin_amdgcn_s_setprio(0);

        // ---- scale + causal mask: key = kt*64+s*16+lg*4+r, q = qrow ----
        float sv[4][4];
        #pragma unroll
        for (int s = 0; s < 4; ++s)
            #pragma unroll
            for (int r = 0; r < 4; ++r)
                sv[s][r] = sf[s][r] * 0.125f;
        if (kt == NT - 1) {
            const int kbase = kt * 64;
            #pragma unroll
            for (int s = 0; s < 4; ++s)
                #pragma unroll
                for (int r = 0; r < 4; ++r)
                    if (kbase + s * 16 + lg * 4 + r > qrow)
                        sv[s][r] = -INFINITY;
        }

        // ---- online softmax: in-lane tree + 2 shfl rounds (lane bits 4,5) ----
        float mx4[4];
        #pragma unroll
        for (int s = 0; s < 4; ++s)
            mx4[s] = fmaxf(fmaxf(sv[s][0], sv[s][1]), fmaxf(sv[s][2], sv[s][3]));
        float mx = fmaxf(fmaxf(mx4[0], mx4[1]), fmaxf(mx4[2], mx4[3]));
        mx = fmaxf(mx, __shfl_xor(mx, 16, 64));
        mx = fmaxf(mx, __shfl_xor(mx, 32, 64));
        const float mnew = fmaxf(mrow, mx);
        const float al   = __expf(mrow - mnew);   // mrow=-inf first tile -> 0
        mrow = mnew;

        float rsum = 0.f;
        #pragma unroll
        for (int s = 0; s < 4; ++s) {
            float p0 = __expf(sv[s][0] - mnew);
            float p1 = __expf(sv[s][1] - mnew);
            float p2 = __expf(sv[s][2] - mnew);
            float p3 = __expf(sv[s][3] - mnew);
            rsum += (p0 + p1) + (p2 + p3);
            ushort4 pk;
            pk.x = f2bf(p0); pk.y = f2bf(p1); pk.z = f2bf(p2); pk.w = f2bf(p3);
            *(ushort4*)&Ps[w][lr][s * 16 + lg * 4] = pk;   // k-contiguous
        }
        rsum += __shfl_xor(rsum, 16, 64);
        rsum += __shfl_xor(rsum, 32, 64);
        lrow = lrow * al + rsum;

        #pragma unroll
        for (int df = 0; df < 4; ++df) acc[df] *= al;      // lane-local rescale

        asm volatile("s_waitcnt lgkmcnt(0)" ::: "memory");
        __builtin_amdgcn_sched_barrier(0);
        s16x8 pa[2];
        #pragma unroll
        for (int kc = 0; kc < 2; ++kc)
            pa[kc] = *(const s16x8*)&Ps[w][lr][kc * 32 + lg * 8];

        // ---- O^T += V^T P^T : 8 MFMA (A = V^T frags from swizzled LDS) ----
        __builtin_amdgcn_s_setprio(1);
        #pragma unroll
        for (int df = 0; df < 4; ++df) {
            const int rb = (df * 16 + lr) * 128;
            s16x8 va0 = *(const s16x8*)((const char*)Vs + rb + ((lg * 16) ^ xorv));
            s16x8 va1 = *(const s16x8*)((const char*)Vs + rb + ((64 + lg * 16) ^ xorv));
            acc[df] = __builtin_amdgcn_mfma_f32_16x16x32_bf16(va0, pa[0], acc[df], 0, 0, 0);
            acc[df] = __builtin_amdgcn_mfma_f32_16x16x32_bf16(va1, pa[1], acc[df], 0, 0, 0);
        }
        __builtin_amdgcn_s_setprio(0);
    }

    // ---- epilogue: lane-local 1/l, write y (8B packed, d-contiguous) ----
    const float inv = 1.f / lrow;
    const int t = qt * 64 + w * 16 + lr;
    unsigned short* yp = y + ((size_t)(b * SEQ) + t) * NEMBD + h * HDIM;
    #pragma unroll
    for (int df = 0; df < 4; ++df) {
        ushort4 pk;
        pk.x = f2bf(acc[df][0] * inv);
        pk.y = f2bf(acc[df][1] * inv);
        pk.z = f2bf(acc[df][2] * inv);
        pk.w = f2bf(acc[df][3] * inv);
        *(ushort4*)(yp + df * 16 + lg * 4) = pk;
    }
}

// ---------------------------------------------------------------------------
extern "C" void kernel_launch(void* const* d_in, const int* in_sizes, int n_in,
                              void* d_out, int out_size, void* d_ws, size_t ws_size,
                              hipStream_t stream)
{
    const float* x      = (const float*)d_in[0];
    const float* w_attn = (const float*)d_in[1];
    const float* b_attn = (const float*)d_in[2];
    const float* w_proj = (const float*)d_in[3];
    const float* b_proj = (const float*)d_in[4];
    float* out = (float*)d_out;

    const int M = BATCH * SEQ;                       // 8192
    const size_t NQKV = (size_t)M * NEMBD;           // 6.29M elements

    unsigned short* xb  = (unsigned short*)d_ws;           // [M][768]
    unsigned short* waT = xb  + NQKV;                      // [2304][768]
    unsigned short* wpT = waT + (size_t)TC * NEMBD;        // [768][768]
    unsigned short* Qb  = wpT + (size_t)NEMBD * NEMBD;     // [B][H][T][D]
    unsigned short* Kb  = Qb  + NQKV;                      // [B][H][T][D]
    unsigned short* Vtb = Kb  + NQKV;                      // [B][H][D][T]
    unsigned short* yb  = Vtb + NQKV;                      // [M][768]

    // 0) bf16 prep
    cast_bf16_kernel<<<(M * NEMBD) / 2048, 256, 0, stream>>>(x, xb, M * NEMBD);
    transpose_cast_kernel<<<dim3(TC / 32, NEMBD / 32), dim3(32, 8), 0, stream>>>(
        w_attn, waT, NEMBD, TC);
    transpose_cast_kernel<<<dim3(NEMBD / 32, NEMBD / 32), dim3(32, 8), 0, stream>>>(
        w_proj, wpT, NEMBD, NEMBD);

    // 1) fused QKV GEMM -> Q, K, V^T buffers (bf16), coalesced epilogue
    gemm_mfma_qkv_kernel<<<dim3(TC / 128, M / 128), 256, 0, stream>>>(
        xb, waT, b_attn, Qb, Kb, Vtb, M, NEMBD);

    // 2) operand-swapped MFMA attention -> yb bf16 [B,T,C]
    attn_mfma_kernel<<<16 * NHEAD * BATCH, 256, 0, stream>>>(Qb, Kb, Vtb, yb);

    // 3) out(fp32) = yb @ wpT^T + b_proj
    gemm_mfma_f32_kernel<<<dim3(NEMBD / 128, M / 128), 256, 0, stream>>>(
        yb, wpT, b_proj, out, M, NEMBD, NEMBD);
}

// Round 9
// 117.314 us; speedup vs baseline: 1.1533x; 1.1052x over previous
//
#include <hip/hip_runtime.h>
#include <hip/hip_bf16.h>
#include <math.h>
#include <type_traits>

// Problem constants (CausalSelfAttention, GPT-2 small shape)
#define BATCH 8
#define SEQ   1024
#define NEMBD 768
#define NHEAD 12
#define HDIM  64
#define TC    (3 * NEMBD)   // 2304

typedef __attribute__((ext_vector_type(4))) float f32x4;
typedef __attribute__((ext_vector_type(8))) short s16x8;   // 8 bf16 in 4 VGPRs

__device__ __forceinline__ unsigned short f2bf(float f) {
    return __builtin_bit_cast(unsigned short, __float2bfloat16(f));
}

// async global->LDS, 16B per lane (dwordx4)
__device__ __forceinline__ void gload_lds16(const void* g, void* l) {
    __builtin_amdgcn_global_load_lds(
        (const __attribute__((address_space(1))) void*)g,
        (__attribute__((address_space(3))) void*)l, 16, 0, 0);
}

// ---------------------------------------------------------------------------
// cast fp32 -> bf16, 8 elements/thread
// ---------------------------------------------------------------------------
__global__ __launch_bounds__(256) void cast_bf16_kernel(
    const float* __restrict__ in, unsigned short* __restrict__ out, int n)
{
    const int i = (blockIdx.x * 256 + threadIdx.x) * 8;
    float4 a = *(const float4*)(in + i);
    float4 b = *(const float4*)(in + i + 4);
    s16x8 v;
    v[0] = f2bf(a.x); v[1] = f2bf(a.y); v[2] = f2bf(a.z); v[3] = f2bf(a.w);
    v[4] = f2bf(b.x); v[5] = f2bf(b.y); v[6] = f2bf(b.z); v[7] = f2bf(b.w);
    *(s16x8*)(out + i) = v;
}

// ---------------------------------------------------------------------------
// transpose + cast: w[K][N] fp32 -> wT[N][K] bf16. 32x32 LDS tiles.
// ---------------------------------------------------------------------------
__global__ __launch_bounds__(256) void transpose_cast_kernel(
    const float* __restrict__ w, unsigned short* __restrict__ wT, int K, int N)
{
    __shared__ float t[32][33];
    const int tx = threadIdx.x, ty = threadIdx.y;   // block (32,8)
    const int n0 = blockIdx.x * 32, k0 = blockIdx.y * 32;
    #pragma unroll
    for (int i = 0; i < 4; ++i)
        t[ty + i * 8][tx] = w[(size_t)(k0 + ty + i * 8) * N + n0 + tx];
    __syncthreads();
    #pragma unroll
    for (int i = 0; i < 4; ++i)
        wT[(size_t)(n0 + ty + i * 8) * K + k0 + tx] = f2bf(t[tx][ty + i * 8]);
}

// ---------------------------------------------------------------------------
// bf16 MFMA GEMM, BK=64, 128x128 tile, 4 waves, single-buffered (m97-style
// 2-barrier loop, but 32 MFMA per barrier pair).  C = A @ Bt^T + bias.
// LDS 32KB total (As/Bs 16KB each) -> high residency.
// Chunk-XOR bank swizzle: LDS[row] physical 16B-chunk p holds logical chunk
// p ^ (row&7); staging pre-applies the inverse on the global SOURCE column
// (gload_lds writes LDS linearly, rule 21); reads XOR the chunk index.
// (row&7) is staging-pass-invariant since passes step rows by 32.
// OUTK=0: fp32 C + bias (direct stores).
// OUTK=1: QKV epilogue -> Q[b,h,t,d], K[b,h,t,d], Vt[b,h,d,t], coalesced
//         via per-wave retile in the (reused) staging LDS.
// XCD-bijective block swizzle: consecutive intra-XCD blocks share A-panel.
// ---------------------------------------------------------------------------
template <int OUTK>
__global__ __launch_bounds__(256) void gemm_bk64_kernel(
    const unsigned short* __restrict__ A,   // [M][K] bf16
    const unsigned short* __restrict__ Bt,  // [N][K] bf16 (= B^T)
    const float* __restrict__ bias,         // [N] fp32
    float* __restrict__ C,                  // OUTK==0
    unsigned short* __restrict__ Qb,        // OUTK==1
    unsigned short* __restrict__ Kb,
    unsigned short* __restrict__ Vtb,
    int M, int N, int K, int nbn)
{
    __shared__ __align__(16) unsigned short As[128 * 64];   // 16KB
    __shared__ __align__(16) unsigned short Bs[128 * 64];   // 16KB

    const int tid  = threadIdx.x;
    const int w    = tid >> 6, lane = tid & 63;
    const int lr   = lane & 15, lg = lane >> 4;
    const int wr   = w >> 1, wc = w & 1;

    // XCD-bijective swizzle (gridDim.x % 8 == 0 for all our launches)
    const int swz = (blockIdx.x & 7) * (gridDim.x >> 3) + (blockIdx.x >> 3);
    const int bm = (swz / nbn) * 128, bn = (swz % nbn) * 128;

    // staging map: pass p covers rows p*32..p*32+31; row = p*32 + (tid>>3),
    // chunk (8 elems) = tid&7, source col pre-inverse-swizzled.
    const int srow = tid >> 3;                       // 0..31
    const int gcol = ((tid & 7) ^ (srow & 7)) * 8;   // inverse swizzle
    const unsigned short* Ag = A  + (size_t)(bm + srow) * K + gcol;
    const unsigned short* Bg = Bt + (size_t)(bn + srow) * K + gcol;
    unsigned short* Al = As + tid * 8;
    unsigned short* Bl = Bs + tid * 8;

    f32x4 acc[4][4];
    #pragma unroll
    for (int m = 0; m < 4; ++m)
        #pragma unroll
        for (int n = 0; n < 4; ++n) acc[m][n] = (f32x4){0.f, 0.f, 0.f, 0.f};

    for (int k0 = 0; k0 < K; k0 += 64) {
        __syncthreads();                             // prior tile consumed
        #pragma unroll
        for (int p = 0; p < 4; ++p) {
            gload_lds16(Ag + (size_t)(p * 32) * K + k0, Al + p * 2048);
            gload_lds16(Bg + (size_t)(p * 32) * K + k0, Bl + p * 2048);
        }
        __syncthreads();                             // tile visible (drained)

        #pragma unroll
        for (int kk = 0; kk < 2; ++kk) {
            s16x8 af[4], bf[4];
            #pragma unroll
            for (int m = 0; m < 4; ++m) {
                const int ar = wr * 64 + m * 16 + lr;
                af[m] = *(const s16x8*)&As[ar * 64 + (((kk * 4 + lg) ^ (ar & 7)) * 8)];
            }
            #pragma unroll
            for (int n = 0; n < 4; ++n) {
                const int br = wc * 64 + n * 16 + lr;
                bf[n] = *(const s16x8*)&Bs[br * 64 + (((kk * 4 + lg) ^ (br & 7)) * 8)];
            }
            __builtin_amdgcn_s_setprio(1);
            #pragma unroll
            for (int m = 0; m < 4; ++m)
                #pragma unroll
                for (int n = 0; n < 4; ++n)
                    acc[m][n] = __builtin_amdgcn_mfma_f32_16x16x32_bf16(
                        af[m], bf[n], acc[m][n], 0, 0, 0);
            __builtin_amdgcn_s_setprio(0);
        }
    }

    if constexpr (OUTK == 0) {
        #pragma unroll
        for (int n = 0; n < 4; ++n) {
            const int col = bn + wc * 64 + n * 16 + lr;
            const float bv = bias[col];
            #pragma unroll
            for (int m = 0; m < 4; ++m) {
                const int row0 = bm + wr * 64 + m * 16 + lg * 4;
                #pragma unroll
                for (int r = 0; r < 4; ++r)
                    C[(size_t)(row0 + r) * N + col] = acc[m][n][r] + bv;
            }
        }
    } else {
        // ---- coalesced QKV epilogue, retile in reused staging LDS ----
        __syncthreads();                             // all frag reads done
        // per-wave 8KB region (64 rows x 8 chunks of 16B, chunk ^= row&7)
        char* Ep = (char*)((w < 2 ? As : Bs)) + (w & 1) * 8192;

        const int region = bn / NEMBD;               // 0=Q, 1=K, 2=V
        const int hh = ((bn % NEMBD) >> 6) + wc;     // head 0..11
        const int row0 = bm + wr * 64;               // 64-aligned
        const int bb = row0 >> 10, t0 = row0 & 1023; // no 1024-crossing

        float bvn[4];
        #pragma unroll
        for (int n = 0; n < 4; ++n) bvn[n] = bias[bn + wc * 64 + n * 16 + lr];

        if (region == 2) {
            // S[d][t]: row = d = n*16+lr; col t = m*16+lg*4+r (ushort4 pack)
            #pragma unroll
            for (int m = 0; m < 4; ++m)
                #pragma unroll
                for (int n = 0; n < 4; ++n) {
                    ushort4 pk;
                    pk.x = f2bf(acc[m][n][0] + bvn[n]);
                    pk.y = f2bf(acc[m][n][1] + bvn[n]);
                    pk.z = f2bf(acc[m][n][2] + bvn[n]);
                    pk.w = f2bf(acc[m][n][3] + bvn[n]);
                    const int row = n * 16 + lr;
                    const int lc  = m * 2 + (lg >> 1);          // logical 16B chunk
                    *(ushort4*)(Ep + row * 128 + ((lc ^ (lr & 7)) * 16)
                                   + (lg & 1) * 8) = pk;
                }
        } else {
            // S[t][d]: row = t = m*16+lg*4+r; col d = n*16+lr (scalar)
            #pragma unroll
            for (int m = 0; m < 4; ++m)
                #pragma unroll
                for (int n = 0; n < 4; ++n)
                    #pragma unroll
                    for (int r = 0; r < 4; ++r) {
                        const int row = m * 16 + lg * 4 + r;
                        const int lc  = n * 2 + (lr >> 3);
                        *(unsigned short*)(Ep + row * 128
                            + ((lc ^ (row & 7)) * 16) + (lr & 7) * 2) =
                            f2bf(acc[m][n][r] + bvn[n]);
                    }
        }
        asm volatile("s_waitcnt lgkmcnt(0)" ::: "memory");
        __builtin_amdgcn_sched_barrier(0);

        const int rr0 = lane >> 3;   // row sub-index 0..7
        const int cc  = lane & 7;    // logical 16B chunk 0..7
        if (region == 2) {
            unsigned short* dst = Vtb + (((size_t)bb * NHEAD + hh) * HDIM) * SEQ + t0;
            #pragma unroll
            for (int it = 0; it < 8; ++it) {
                const int d = it * 8 + rr0;
                s16x8 v = *(const s16x8*)(Ep + d * 128 + ((cc ^ (d & 7)) * 16));
                *(s16x8*)(dst + (size_t)d * SEQ + cc * 8) = v;
            }
        } else {
            unsigned short* dst = (region == 0 ? Qb : Kb)
                                + ((size_t)bb * NHEAD + hh) * SEQ * HDIM;
            #pragma unroll
            for (int it = 0; it < 8; ++it) {
                const int t = it * 8 + rr0;
                s16x8 v = *(const s16x8*)(Ep + t * 128 + ((cc ^ (t & 7)) * 16));
                *(s16x8*)(dst + (size_t)(t0 + t) * HDIM + cc * 8) = v;
            }
        }
    }
}

// ---------------------------------------------------------------------------
// Flash attention, bf16 MFMA, operand-swapped (S^T) softmax.
// 1-D grid 1536 = 8 XCD-classes x 12 bh-groups x 16 q-tiles (unchanged).
// ---------------------------------------------------------------------------
__global__ __launch_bounds__(256) void attn_mfma_kernel(
    const unsigned short* __restrict__ Qb,
    const unsigned short* __restrict__ Kb,
    const unsigned short* __restrict__ Vtb,
    unsigned short* __restrict__ y)
{
    const int bid = blockIdx.x;
    const int xcd = bid & 7;
    const int grp = bid >> 3;             // 0..191
    const int qt  = 15 - (grp & 15);      // long blocks first within class
    const int bh  = xcd + 8 * (grp >> 4); // 0..95
    const int b   = bh / NHEAD, h = bh % NHEAD;

    const int tid  = threadIdx.x;
    const int w    = tid >> 6;
    const int lane = tid & 63;
    const int lr   = lane & 15;
    const int lg   = lane >> 4;

    __shared__ __align__(16) unsigned short Ks[64 * 64];    // swizzled [k][d]
    __shared__ __align__(16) unsigned short Vs[64 * 64];    // swizzled [d][t]
    __shared__ __align__(16) unsigned short Ps[4][16][72];  // per-wave P [q][k]

    const unsigned short* Qg = Qb  + ((size_t)bh * SEQ + qt * 64 + w * 16) * HDIM;
    const unsigned short* Kg = Kb  + (size_t)bh * SEQ * HDIM;
    const unsigned short* Vg = Vtb + (size_t)bh * HDIM * SEQ;

    // Q B-frags: col q = lr, kdim d = kc*32 + lg*8 + j
    s16x8 qf[2];
    #pragma unroll
    for (int kc = 0; kc < 2; ++kc)
        qf[kc] = *(const s16x8*)(Qg + (size_t)lr * HDIM + kc * 32 + lg * 8);

    f32x4 acc[4];                         // O^T frags: row d = df*16+lg*4+r, col q = lr
    #pragma unroll
    for (int df = 0; df < 4; ++df) acc[df] = (f32x4){0.f, 0.f, 0.f, 0.f};
    float mrow = -INFINITY, lrow = 0.f;

    // staging maps: thread -> row tid>>2, 16-elem chunk (tid&3)
    const int sr = tid >> 2;
    const int sc = (tid & 3) * 16;
    const unsigned short* Kgr = Kg + (size_t)sr * HDIM + sc;
    const unsigned short* Vgr = Vg + (size_t)sr * SEQ  + sc;
    const int swz0 = sr * 128 + ((sc * 2)      ^ ((sr & 7) << 4));
    const int swz1 = sr * 128 + ((sc * 2 + 16) ^ ((sr & 7) << 4));
    const int xorv = (lr & 7) << 4;       // read-side swizzle

    const int NT   = qt + 1;
    const int qrow = qt * 64 + w * 16 + lr;

    // prologue: tile-0 loads into regs
    s16x8 krA = *(const s16x8*)(Kgr);
    s16x8 krB = *(const s16x8*)(Kgr + 8);
    s16x8 vrA = *(const s16x8*)(Vgr);
    s16x8 vrB = *(const s16x8*)(Vgr + 8);

    for (int kt = 0; kt < NT; ++kt) {
        __syncthreads();                  // LDS consumed
        *(s16x8*)((char*)Ks + swz0) = krA;
        *(s16x8*)((char*)Ks + swz1) = krB;
        *(s16x8*)((char*)Vs + swz0) = vrA;
        *(s16x8*)((char*)Vs + swz1) = vrB;
        __syncthreads();                  // tile visible
        if (kt + 1 < NT) {                // T14: issue next tile's loads now
            krA = *(const s16x8*)(Kgr + (size_t)(kt + 1) * 64 * HDIM);
            krB = *(const s16x8*)(Kgr + (size_t)(kt + 1) * 64 * HDIM + 8);
            vrA = *(const s16x8*)(Vgr + (kt + 1) * 64);
            vrB = *(const s16x8*)(Vgr + (kt + 1) * 64 + 8);
        }

        // ---- S^T = K Q : 8 MFMA (A = K frags from swizzled LDS, B = Q) ----
        f32x4 sf[4];
        __builtin_amdgcn_s_setprio(1);
        #pragma unroll
        for (int s = 0; s < 4; ++s) {
            const int rb = (s * 16 + lr) * 128;
            s16x8 a0 = *(const s16x8*)((const char*)Ks + rb + ((lg * 16) ^ xorv));
            s16x8 a1 = *(const s16x8*)((const char*)Ks + rb + ((64 + lg * 16) ^ xorv));
            sf[s] = __builtin_amdgcn_mfma_f32_16x16x32_bf16(
                a0, qf[0], (f32x4){0.f, 0.f, 0.f, 0.f}, 0, 0, 0);
            sf[s] = __builtin_amdgcn_mfma_f32_16x16x32_bf16(a1, qf[1], sf[s], 0, 0, 0);
        }
        __builtin_amdgcn_s_setprio(0);

        // ---- scale + causal mask: key = kt*64+s*16+lg*4+r, q = qrow ----
        float sv[4][4];
        #pragma unroll
        for (int s = 0; s < 4; ++s)
            #pragma unroll
            for (int r = 0; r < 4; ++r)
                sv[s][r] = sf[s][r] * 0.125f;
        if (kt == NT - 1) {
            const int kbase = kt * 64;
            #pragma unroll
            for (int s = 0; s < 4; ++s)
                #pragma unroll
                for (int r = 0; r < 4; ++r)
                    if (kbase + s * 16 + lg * 4 + r > qrow)
                        sv[s][r] = -INFINITY;
        }

        // ---- online softmax: in-lane tree + 2 shfl rounds (lane bits 4,5) ----
        float mx4[4];
        #pragma unroll
        for (int s = 0; s < 4; ++s)
            mx4[s] = fmaxf(fmaxf(sv[s][0], sv[s][1]), fmaxf(sv[s][2], sv[s][3]));
        float mx = fmaxf(fmaxf(mx4[0], mx4[1]), fmaxf(mx4[2], mx4[3]));
        mx = fmaxf(mx, __shfl_xor(mx, 16, 64));
        mx = fmaxf(mx, __shfl_xor(mx, 32, 64));
        const float mnew = fmaxf(mrow, mx);
        const float al   = __expf(mrow - mnew);   // mrow=-inf first tile -> 0
        mrow = mnew;

        float rsum = 0.f;
        #pragma unroll
        for (int s = 0; s < 4; ++s) {
            float p0 = __expf(sv[s][0] - mnew);
            float p1 = __expf(sv[s][1] - mnew);
            float p2 = __expf(sv[s][2] - mnew);
            float p3 = __expf(sv[s][3] - mnew);
            rsum += (p0 + p1) + (p2 + p3);
            ushort4 pk;
            pk.x = f2bf(p0); pk.y = f2bf(p1); pk.z = f2bf(p2); pk.w = f2bf(p3);
            *(ushort4*)&Ps[w][lr][s * 16 + lg * 4] = pk;   // k-contiguous
        }
        rsum += __shfl_xor(rsum, 16, 64);
        rsum += __shfl_xor(rsum, 32, 64);
        lrow = lrow * al + rsum;

        #pragma unroll
        for (int df = 0; df < 4; ++df) acc[df] *= al;      // lane-local rescale

        asm volatile("s_waitcnt lgkmcnt(0)" ::: "memory");
        __builtin_amdgcn_sched_barrier(0);
        s16x8 pa[2];
        #pragma unroll
        for (int kc = 0; kc < 2; ++kc)
            pa[kc] = *(const s16x8*)&Ps[w][lr][kc * 32 + lg * 8];

        // ---- O^T += V^T P^T : 8 MFMA (A = V^T frags from swizzled LDS) ----
        __builtin_amdgcn_s_setprio(1);
        #pragma unroll
        for (int df = 0; df < 4; ++df) {
            const int rb = (df * 16 + lr) * 128;
            s16x8 va0 = *(const s16x8*)((const char*)Vs + rb + ((lg * 16) ^ xorv));
            s16x8 va1 = *(const s16x8*)((const char*)Vs + rb + ((64 + lg * 16) ^ xorv));
            acc[df] = __builtin_amdgcn_mfma_f32_16x16x32_bf16(va0, pa[0], acc[df], 0, 0, 0);
            acc[df] = __builtin_amdgcn_mfma_f32_16x16x32_bf16(va1, pa[1], acc[df], 0, 0, 0);
        }
        __builtin_amdgcn_s_setprio(0);
    }

    // ---- epilogue: lane-local 1/l, write y (8B packed, d-contiguous) ----
    const float inv = 1.f / lrow;
    const int t = qt * 64 + w * 16 + lr;
    unsigned short* yp = y + ((size_t)(b * SEQ) + t) * NEMBD + h * HDIM;
    #pragma unroll
    for (int df = 0; df < 4; ++df) {
        ushort4 pk;
        pk.x = f2bf(acc[df][0] * inv);
        pk.y = f2bf(acc[df][1] * inv);
        pk.z = f2bf(acc[df][2] * inv);
        pk.w = f2bf(acc[df][3] * inv);
        *(ushort4*)(yp + df * 16 + lg * 4) = pk;
    }
}

// ---------------------------------------------------------------------------
extern "C" void kernel_launch(void* const* d_in, const int* in_sizes, int n_in,
                              void* d_out, int out_size, void* d_ws, size_t ws_size,
                              hipStream_t stream)
{
    const float* x      = (const float*)d_in[0];
    const float* w_attn = (const float*)d_in[1];
    const float* b_attn = (const float*)d_in[2];
    const float* w_proj = (const float*)d_in[3];
    const float* b_proj = (const float*)d_in[4];
    float* out = (float*)d_out;

    const int M = BATCH * SEQ;                       // 8192
    const size_t NQKV = (size_t)M * NEMBD;           // 6.29M elements

    unsigned short* xb  = (unsigned short*)d_ws;           // [M][768]
    unsigned short* waT = xb  + NQKV;                      // [2304][768]
    unsigned short* wpT = waT + (size_t)TC * NEMBD;        // [768][768]
    unsigned short* Qb  = wpT + (size_t)NEMBD * NEMBD;     // [B][H][T][D]
    unsigned short* Kb  = Qb  + NQKV;                      // [B][H][T][D]
    unsigned short* Vtb = Kb  + NQKV;                      // [B][H][D][T]
    unsigned short* yb  = Vtb + NQKV;                      // [M][768]

    // 0) bf16 prep
    cast_bf16_kernel<<<(M * NEMBD) / 2048, 256, 0, stream>>>(x, xb, M * NEMBD);
    transpose_cast_kernel<<<dim3(TC / 32, NEMBD / 32), dim3(32, 8), 0, stream>>>(
        w_attn, waT, NEMBD, TC);
    transpose_cast_kernel<<<dim3(NEMBD / 32, NEMBD / 32), dim3(32, 8), 0, stream>>>(
        w_proj, wpT, NEMBD, NEMBD);

    // 1) fused QKV GEMM (BK=64) -> Q, K, V^T buffers (bf16), coalesced epilogue
    gemm_bk64_kernel<1><<<(TC / 128) * (M / 128), 256, 0, stream>>>(
        xb, waT, b_attn, nullptr, Qb, Kb, Vtb, M, TC, NEMBD, TC / 128);

    // 2) operand-swapped MFMA attention -> yb bf16 [B,T,C]
    attn_mfma_kernel<<<16 * NHEAD * BATCH, 256, 0, stream>>>(Qb, Kb, Vtb, yb);

    // 3) out(fp32) = yb @ wpT^T + b_proj (BK=64)
    gemm_bk64_kernel<0><<<(NEMBD / 128) * (M / 128), 256, 0, stream>>>(
        yb, wpT, b_proj, out, nullptr, nullptr, nullptr, M, NEMBD, NEMBD, NEMBD / 128);
}

// Round 10
// 116.864 us; speedup vs baseline: 1.1577x; 1.0038x over previous
//
#include <hip/hip_runtime.h>
#include <hip/hip_bf16.h>
#include <math.h>
#include <type_traits>

// Problem constants (CausalSelfAttention, GPT-2 small shape)
#define BATCH 8
#define SEQ   1024
#define NEMBD 768
#define NHEAD 12
#define HDIM  64
#define TC    (3 * NEMBD)   // 2304

typedef __attribute__((ext_vector_type(4))) float f32x4;
typedef __attribute__((ext_vector_type(8))) short s16x8;   // 8 bf16 in 4 VGPRs

__device__ __forceinline__ unsigned short f2bf(float f) {
    return __builtin_bit_cast(unsigned short, __float2bfloat16(f));
}

// async global->LDS, 16B per lane (dwordx4)
__device__ __forceinline__ void gload_lds16(const void* g, void* l) {
    __builtin_amdgcn_global_load_lds(
        (const __attribute__((address_space(1))) void*)g,
        (__attribute__((address_space(3))) void*)l, 16, 0, 0);
}

// ---------------------------------------------------------------------------
// cast fp32 -> bf16, 8 elements/thread
// ---------------------------------------------------------------------------
__global__ __launch_bounds__(256) void cast_bf16_kernel(
    const float* __restrict__ in, unsigned short* __restrict__ out, int n)
{
    const int i = (blockIdx.x * 256 + threadIdx.x) * 8;
    float4 a = *(const float4*)(in + i);
    float4 b = *(const float4*)(in + i + 4);
    s16x8 v;
    v[0] = f2bf(a.x); v[1] = f2bf(a.y); v[2] = f2bf(a.z); v[3] = f2bf(a.w);
    v[4] = f2bf(b.x); v[5] = f2bf(b.y); v[6] = f2bf(b.z); v[7] = f2bf(b.w);
    *(s16x8*)(out + i) = v;
}

// ---------------------------------------------------------------------------
// transpose + cast: w[K][N] fp32 -> wT[N][K] bf16. 32x32 LDS tiles.
// ---------------------------------------------------------------------------
__global__ __launch_bounds__(256) void transpose_cast_kernel(
    const float* __restrict__ w, unsigned short* __restrict__ wT, int K, int N)
{
    __shared__ float t[32][33];
    const int tx = threadIdx.x, ty = threadIdx.y;   // block (32,8)
    const int n0 = blockIdx.x * 32, k0 = blockIdx.y * 32;
    #pragma unroll
    for (int i = 0; i < 4; ++i)
        t[ty + i * 8][tx] = w[(size_t)(k0 + ty + i * 8) * N + n0 + tx];
    __syncthreads();
    #pragma unroll
    for (int i = 0; i < 4; ++i)
        wT[(size_t)(n0 + ty + i * 8) * K + k0 + tx] = f2bf(t[tx][ty + i * 8]);
}

// ---------------------------------------------------------------------------
// 3-buffer counted-vmcnt bf16 MFMA GEMM: C = A @ Bt^T + bias.
// 128x128 tile, BK=32, 4 waves, LDS = 3 x 16KB rotating K-tile buffers
// (48KB -> 3 blocks/CU).  Depth-2 global_load_lds prefetch; per iter:
//   stage(t+2) -> ds_read frags(buf t) -> 16 MFMA -> vmcnt(4) -> s_barrier
// vmcnt(4) leaves tile t+2's 4 loads in flight (T4: never drain to 0).
// Chunk-XOR swizzle (validated r7/r8): physical chunk c of row holds logical
// chunk c ^ ((row>>1)&3); staging pre-applies inverse on the global SOURCE
// (gload_lds writes LDS linearly, rule 21); reads XOR the chunk index.
// (row>>1)&3 is pass-invariant (passes step rows by 64).
//
// Hazard analysis (buffers rotate mod 3):
//   iter t reads buf[t%3] (staged at t-2; completed by iter t-1's vmcnt(4),
//   agreed by its barrier).  iter t stages into buf[(t+2)%3] = buf[(t-1)%3],
//   whose last ds_reads completed before iter t-1's MFMAs and hence before
//   the iter t-1 barrier that precedes this stage issue.
// OUTK=0: fp32 C + bias.  OUTK=1: coalesced QKV epilogue (Ep retile reuses
// the first 32KB of buffer LDS after the final barrier).
// ---------------------------------------------------------------------------
template <int OUTK>
__global__ __launch_bounds__(256) void gemm_pipe3_kernel(
    const unsigned short* __restrict__ A,   // [M][K] bf16
    const unsigned short* __restrict__ Bt,  // [N][K] bf16 (= B^T)
    const float* __restrict__ bias,         // [N] fp32
    float* __restrict__ C,                  // OUTK==0
    unsigned short* __restrict__ Qb,        // OUTK==1
    unsigned short* __restrict__ Kb,
    unsigned short* __restrict__ Vtb,
    int M, int N, int K, int nbn)
{
    constexpr int BUF = 16384;                       // bytes per K-tile buffer
    __shared__ __align__(16) char SM[3 * BUF];       // 48KB

    const int tid  = threadIdx.x;
    const int w    = tid >> 6, lane = tid & 63;
    const int lr   = lane & 15, lg = lane >> 4;
    const int wr   = w >> 1, wc = w & 1;

    // XCD-bijective swizzle (gridDim.x % 8 == 0 for all our launches)
    const int swz = (blockIdx.x & 7) * (gridDim.x >> 3) + (blockIdx.x >> 3);
    const int bm = (swz / nbn) * 128, bn = (swz % nbn) * 128;

    // staging: per tile 4 gloads/thread (A x2 passes, B x2 passes),
    // pass p covers rows p*64 + (tid>>2); chunk = tid&3, source col
    // pre-inverse-swizzled.  LDS dest linear: p*4096 + tid*16.
    const int srow = tid >> 2;                       // 0..63
    const int gcol = ((tid & 3) ^ ((srow >> 1) & 3)) * 8;
    const unsigned short* Ag = A  + (size_t)(bm + srow) * K + gcol;
    const unsigned short* Bg = Bt + (size_t)(bn + srow) * K + gcol;

    const int NT = K >> 5;                           // K/32 = 24

    f32x4 acc[4][4];
    #pragma unroll
    for (int m = 0; m < 4; ++m)
        #pragma unroll
        for (int n = 0; n < 4; ++n) acc[m][n] = (f32x4){0.f, 0.f, 0.f, 0.f};

    auto stage = [&](int t) {
        const int k0 = t << 5;
        char* buf = SM + (t % 3) * BUF;
        #pragma unroll
        for (int p = 0; p < 2; ++p)
            gload_lds16(Ag + (size_t)(p * 64) * K + k0,
                        buf + p * 4096 + tid * 16);
        #pragma unroll
        for (int p = 0; p < 2; ++p)
            gload_lds16(Bg + (size_t)(p * 64) * K + k0,
                        buf + 8192 + p * 4096 + tid * 16);
    };

    // prologue: tiles 0,1 in flight; wait tile 0 (tile 1's 4 stay outstanding)
    stage(0);
    stage(1);
    asm volatile("s_waitcnt vmcnt(4)" ::: "memory");
    __builtin_amdgcn_sched_barrier(0);
    __builtin_amdgcn_s_barrier();
    __builtin_amdgcn_sched_barrier(0);

    for (int t = 0; t < NT; ++t) {
        const char* buf = SM + (t % 3) * BUF;
        const bool more = (t + 2 < NT);
        if (more) stage(t + 2);

        s16x8 af[4], bfr[4];
        #pragma unroll
        for (int m = 0; m < 4; ++m) {
            const int ar = wr * 64 + m * 16 + lr;
            af[m] = *(const s16x8*)(buf + ar * 64 + ((lg ^ ((ar >> 1) & 3)) * 16));
        }
        #pragma unroll
        for (int n = 0; n < 4; ++n) {
            const int br = wc * 64 + n * 16 + lr;
            bfr[n] = *(const s16x8*)(buf + 8192 + br * 64
                                         + ((lg ^ ((br >> 1) & 3)) * 16));
        }

        __builtin_amdgcn_s_setprio(1);
        #pragma unroll
        for (int m = 0; m < 4; ++m)
            #pragma unroll
            for (int n = 0; n < 4; ++n)
                acc[m][n] = __builtin_amdgcn_mfma_f32_16x16x32_bf16(
                    af[m], bfr[n], acc[m][n], 0, 0, 0);
        __builtin_amdgcn_s_setprio(0);

        if (more) asm volatile("s_waitcnt vmcnt(4)" ::: "memory");
        else      asm volatile("s_waitcnt vmcnt(0)" ::: "memory");
        __builtin_amdgcn_sched_barrier(0);
        __builtin_amdgcn_s_barrier();
        __builtin_amdgcn_sched_barrier(0);
    }

    if constexpr (OUTK == 0) {
        #pragma unroll
        for (int n = 0; n < 4; ++n) {
            const int col = bn + wc * 64 + n * 16 + lr;
            const float bv = bias[col];
            #pragma unroll
            for (int m = 0; m < 4; ++m) {
                const int row0 = bm + wr * 64 + m * 16 + lg * 4;
                #pragma unroll
                for (int r = 0; r < 4; ++r)
                    C[(size_t)(row0 + r) * N + col] = acc[m][n][r] + bv;
            }
        }
    } else {
        // ---- coalesced QKV epilogue, retile in reused buffer LDS ----
        // (final loop barrier fences all frag reads; per-wave 8KB region)
        char* Ep = SM + w * 8192;

        const int region = bn / NEMBD;               // 0=Q, 1=K, 2=V
        const int hh = ((bn % NEMBD) >> 6) + wc;     // head 0..11
        const int row0 = bm + wr * 64;               // 64-aligned
        const int bb = row0 >> 10, t0 = row0 & 1023; // no 1024-crossing

        float bvn[4];
        #pragma unroll
        for (int n = 0; n < 4; ++n) bvn[n] = bias[bn + wc * 64 + n * 16 + lr];

        if (region == 2) {
            // S[d][t]: row = d = n*16+lr; col t = m*16+lg*4+r (ushort4 pack)
            #pragma unroll
            for (int m = 0; m < 4; ++m)
                #pragma unroll
                for (int n = 0; n < 4; ++n) {
                    ushort4 pk;
                    pk.x = f2bf(acc[m][n][0] + bvn[n]);
                    pk.y = f2bf(acc[m][n][1] + bvn[n]);
                    pk.z = f2bf(acc[m][n][2] + bvn[n]);
                    pk.w = f2bf(acc[m][n][3] + bvn[n]);
                    const int row = n * 16 + lr;
                    const int lc  = m * 2 + (lg >> 1);        // logical 16B chunk
                    *(ushort4*)(Ep + row * 128 + ((lc ^ (lr & 7)) * 16)
                                   + (lg & 1) * 8) = pk;
                }
        } else {
            // S[t][d]: row = t = m*16+lg*4+r; col d = n*16+lr (scalar)
            #pragma unroll
            for (int m = 0; m < 4; ++m)
                #pragma unroll
                for (int n = 0; n < 4; ++n)
                    #pragma unroll
                    for (int r = 0; r < 4; ++r) {
                        const int row = m * 16 + lg * 4 + r;
                        const int lc  = n * 2 + (lr >> 3);
                        *(unsigned short*)(Ep + row * 128
                            + ((lc ^ (row & 7)) * 16) + (lr & 7) * 2) =
                            f2bf(acc[m][n][r] + bvn[n]);
                    }
        }
        asm volatile("s_waitcnt lgkmcnt(0)" ::: "memory");
        __builtin_amdgcn_sched_barrier(0);

        const int rr0 = lane >> 3;   // row sub-index 0..7
        const int cc  = lane & 7;    // logical 16B chunk 0..7
        if (region == 2) {
            unsigned short* dst = Vtb + (((size_t)bb * NHEAD + hh) * HDIM) * SEQ + t0;
            #pragma unroll
            for (int it = 0; it < 8; ++it) {
                const int d = it * 8 + rr0;
                s16x8 v = *(const s16x8*)(Ep + d * 128 + ((cc ^ (d & 7)) * 16));
                *(s16x8*)(dst + (size_t)d * SEQ + cc * 8) = v;
            }
        } else {
            unsigned short* dst = (region == 0 ? Qb : Kb)
                                + ((size_t)bb * NHEAD + hh) * SEQ * HDIM;
            #pragma unroll
            for (int it = 0; it < 8; ++it) {
                const int t = it * 8 + rr0;
                s16x8 v = *(const s16x8*)(Ep + t * 128 + ((cc ^ (t & 7)) * 16));
                *(s16x8*)(dst + (size_t)(t0 + t) * HDIM + cc * 8) = v;
            }
        }
    }
}

// ---------------------------------------------------------------------------
// Flash attention, bf16 MFMA, operand-swapped (S^T) softmax.
// 1-D grid 1536 = 8 XCD-classes x 12 bh-groups x 16 q-tiles (unchanged).
// ---------------------------------------------------------------------------
__global__ __launch_bounds__(256) void attn_mfma_kernel(
    const unsigned short* __restrict__ Qb,
    const unsigned short* __restrict__ Kb,
    const unsigned short* __restrict__ Vtb,
    unsigned short* __restrict__ y)
{
    const int bid = blockIdx.x;
    const int xcd = bid & 7;
    const int grp = bid >> 3;             // 0..191
    const int qt  = 15 - (grp & 15);      // long blocks first within class
    const int bh  = xcd + 8 * (grp >> 4); // 0..95
    const int b   = bh / NHEAD, h = bh % NHEAD;

    const int tid  = threadIdx.x;
    const int w    = tid >> 6;
    const int lane = tid & 63;
    const int lr   = lane & 15;
    const int lg   = lane >> 4;

    __shared__ __align__(16) unsigned short Ks[64 * 64];    // swizzled [k][d]
    __shared__ __align__(16) unsigned short Vs[64 * 64];    // swizzled [d][t]
    __shared__ __align__(16) unsigned short Ps[4][16][72];  // per-wave P [q][k]

    const unsigned short* Qg = Qb  + ((size_t)bh * SEQ + qt * 64 + w * 16) * HDIM;
    const unsigned short* Kg = Kb  + (size_t)bh * SEQ * HDIM;
    const unsigned short* Vg = Vtb + (size_t)bh * HDIM * SEQ;

    // Q B-frags: col q = lr, kdim d = kc*32 + lg*8 + j
    s16x8 qf[2];
    #pragma unroll
    for (int kc = 0; kc < 2; ++kc)
        qf[kc] = *(const s16x8*)(Qg + (size_t)lr * HDIM + kc * 32 + lg * 8);

    f32x4 acc[4];                         // O^T frags: row d = df*16+lg*4+r, col q = lr
    #pragma unroll
    for (int df = 0; df < 4; ++df) acc[df] = (f32x4){0.f, 0.f, 0.f, 0.f};
    float mrow = -INFINITY, lrow = 0.f;

    // staging maps: thread -> row tid>>2, 16-elem chunk (tid&3)
    const int sr = tid >> 2;
    const int sc = (tid & 3) * 16;
    const unsigned short* Kgr = Kg + (size_t)sr * HDIM + sc;
    const unsigned short* Vgr = Vg + (size_t)sr * SEQ  + sc;
    const int swz0 = sr * 128 + ((sc * 2)      ^ ((sr & 7) << 4));
    const int swz1 = sr * 128 + ((sc * 2 + 16) ^ ((sr & 7) << 4));
    const int xorv = (lr & 7) << 4;       // read-side swizzle

    const int NT   = qt + 1;
    const int qrow = qt * 64 + w * 16 + lr;

    // prologue: tile-0 loads into regs
    s16x8 krA = *(const s16x8*)(Kgr);
    s16x8 krB = *(const s16x8*)(Kgr + 8);
    s16x8 vrA = *(const s16x8*)(Vgr);
    s16x8 vrB = *(const s16x8*)(Vgr + 8);

    for (int kt = 0; kt < NT; ++kt) {
        __syncthreads();                  // LDS consumed
        *(s16x8*)((char*)Ks + swz0) = krA;
        *(s16x8*)((char*)Ks + swz1) = krB;
        *(s16x8*)((char*)Vs + swz0) = vrA;
        *(s16x8*)((char*)Vs + swz1) = vrB;
        __syncthreads();                  // tile visible
        if (kt + 1 < NT) {                // T14: issue next tile's loads now
            krA = *(const s16x8*)(Kgr + (size_t)(kt + 1) * 64 * HDIM);
            krB = *(const s16x8*)(Kgr + (size_t)(kt + 1) * 64 * HDIM + 8);
            vrA = *(const s16x8*)(Vgr + (kt + 1) * 64);
            vrB = *(const s16x8*)(Vgr + (kt + 1) * 64 + 8);
        }

        // ---- S^T = K Q : 8 MFMA (A = K frags from swizzled LDS, B = Q) ----
        f32x4 sf[4];
        __builtin_amdgcn_s_setprio(1);
        #pragma unroll
        for (int s = 0; s < 4; ++s) {
            const int rb = (s * 16 + lr) * 128;
            s16x8 a0 = *(const s16x8*)((const char*)Ks + rb + ((lg * 16) ^ xorv));
            s16x8 a1 = *(const s16x8*)((const char*)Ks + rb + ((64 + lg * 16) ^ xorv));
            sf[s] = __builtin_amdgcn_mfma_f32_16x16x32_bf16(
                a0, qf[0], (f32x4){0.f, 0.f, 0.f, 0.f}, 0, 0, 0);
            sf[s] = __builtin_amdgcn_mfma_f32_16x16x32_bf16(a1, qf[1], sf[s], 0, 0, 0);
        }
        __builtin_amdgcn_s_setprio(0);

        // ---- scale + causal mask: key = kt*64+s*16+lg*4+r, q = qrow ----
        float sv[4][4];
        #pragma unroll
        for (int s = 0; s < 4; ++s)
            #pragma unroll
            for (int r = 0; r < 4; ++r)
                sv[s][r] = sf[s][r] * 0.125f;
        if (kt == NT - 1) {
            const int kbase = kt * 64;
            #pragma unroll
            for (int s = 0; s < 4; ++s)
                #pragma unroll
                for (int r = 0; r < 4; ++r)
                    if (kbase + s * 16 + lg * 4 + r > qrow)
                        sv[s][r] = -INFINITY;
        }

        // ---- online softmax: in-lane tree + 2 shfl rounds (lane bits 4,5) ----
        float mx4[4];
        #pragma unroll
        for (int s = 0; s < 4; ++s)
            mx4[s] = fmaxf(fmaxf(sv[s][0], sv[s][1]), fmaxf(sv[s][2], sv[s][3]));
        float mx = fmaxf(fmaxf(mx4[0], mx4[1]), fmaxf(mx4[2], mx4[3]));
        mx = fmaxf(mx, __shfl_xor(mx, 16, 64));
        mx = fmaxf(mx, __shfl_xor(mx, 32, 64));
        const float mnew = fmaxf(mrow, mx);
        const float al   = __expf(mrow - mnew);   // mrow=-inf first tile -> 0
        mrow = mnew;

        float rsum = 0.f;
        #pragma unroll
        for (int s = 0; s < 4; ++s) {
            float p0 = __expf(sv[s][0] - mnew);
            float p1 = __expf(sv[s][1] - mnew);
            float p2 = __expf(sv[s][2] - mnew);
            float p3 = __expf(sv[s][3] - mnew);
            rsum += (p0 + p1) + (p2 + p3);
            ushort4 pk;
            pk.x = f2bf(p0); pk.y = f2bf(p1); pk.z = f2bf(p2); pk.w = f2bf(p3);
            *(ushort4*)&Ps[w][lr][s * 16 + lg * 4] = pk;   // k-contiguous
        }
        rsum += __shfl_xor(rsum, 16, 64);
        rsum += __shfl_xor(rsum, 32, 64);
        lrow = lrow * al + rsum;

        #pragma unroll
        for (int df = 0; df < 4; ++df) acc[df] *= al;      // lane-local rescale

        asm volatile("s_waitcnt lgkmcnt(0)" ::: "memory");
        __builtin_amdgcn_sched_barrier(0);
        s16x8 pa[2];
        #pragma unroll
        for (int kc = 0; kc < 2; ++kc)
            pa[kc] = *(const s16x8*)&Ps[w][lr][kc * 32 + lg * 8];

        // ---- O^T += V^T P^T : 8 MFMA (A = V^T frags from swizzled LDS) ----
        __builtin_amdgcn_s_setprio(1);
        #pragma unroll
        for (int df = 0; df < 4; ++df) {
            const int rb = (df * 16 + lr) * 128;
            s16x8 va0 = *(const s16x8*)((const char*)Vs + rb + ((lg * 16) ^ xorv));
            s16x8 va1 = *(const s16x8*)((const char*)Vs + rb + ((64 + lg * 16) ^ xorv));
            acc[df] = __builtin_amdgcn_mfma_f32_16x16x32_bf16(va0, pa[0], acc[df], 0, 0, 0);
            acc[df] = __builtin_amdgcn_mfma_f32_16x16x32_bf16(va1, pa[1], acc[df], 0, 0, 0);
        }
        __builtin_amdgcn_s_setprio(0);
    }

    // ---- epilogue: lane-local 1/l, write y (8B packed, d-contiguous) ----
    const float inv = 1.f / lrow;
    const int t = qt * 64 + w * 16 + lr;
    unsigned short* yp = y + ((size_t)(b * SEQ) + t) * NEMBD + h * HDIM;
    #pragma unroll
    for (int df = 0; df < 4; ++df) {
        ushort4 pk;
        pk.x = f2bf(acc[df][0] * inv);
        pk.y = f2bf(acc[df][1] * inv);
        pk.z = f2bf(acc[df][2] * inv);
        pk.w = f2bf(acc[df][3] * inv);
        *(ushort4*)(yp + df * 16 + lg * 4) = pk;
    }
}

// ---------------------------------------------------------------------------
extern "C" void kernel_launch(void* const* d_in, const int* in_sizes, int n_in,
                              void* d_out, int out_size, void* d_ws, size_t ws_size,
                              hipStream_t stream)
{
    const float* x      = (const float*)d_in[0];
    const float* w_attn = (const float*)d_in[1];
    const float* b_attn = (const float*)d_in[2];
    const float* w_proj = (const float*)d_in[3];
    const float* b_proj = (const float*)d_in[4];
    float* out = (float*)d_out;

    const int M = BATCH * SEQ;                       // 8192
    const size_t NQKV = (size_t)M * NEMBD;           // 6.29M elements

    unsigned short* xb  = (unsigned short*)d_ws;           // [M][768]
    unsigned short* waT = xb  + NQKV;                      // [2304][768]
    unsigned short* wpT = waT + (size_t)TC * NEMBD;        // [768][768]
    unsigned short* Qb  = wpT + (size_t)NEMBD * NEMBD;     // [B][H][T][D]
    unsigned short* Kb  = Qb  + NQKV;                      // [B][H][T][D]
    unsigned short* Vtb = Kb  + NQKV;                      // [B][H][D][T]
    unsigned short* yb  = Vtb + NQKV;                      // [M][768]

    // 0) bf16 prep
    cast_bf16_kernel<<<(M * NEMBD) / 2048, 256, 0, stream>>>(x, xb, M * NEMBD);
    transpose_cast_kernel<<<dim3(TC / 32, NEMBD / 32), dim3(32, 8), 0, stream>>>(
        w_attn, waT, NEMBD, TC);
    transpose_cast_kernel<<<dim3(NEMBD / 32, NEMBD / 32), dim3(32, 8), 0, stream>>>(
        w_proj, wpT, NEMBD, NEMBD);

    // 1) fused QKV GEMM (3-buffer pipeline) -> Q, K, V^T buffers (bf16)
    gemm_pipe3_kernel<1><<<(TC / 128) * (M / 128), 256, 0, stream>>>(
        xb, waT, b_attn, nullptr, Qb, Kb, Vtb, M, TC, NEMBD, TC / 128);

    // 2) operand-swapped MFMA attention -> yb bf16 [B,T,C]
    attn_mfma_kernel<<<16 * NHEAD * BATCH, 256, 0, stream>>>(Qb, Kb, Vtb, yb);

    // 3) out(fp32) = yb @ wpT^T + b_proj (3-buffer pipeline)
    gemm_pipe3_kernel<0><<<(NEMBD / 128) * (M / 128), 256, 0, stream>>>(
        yb, wpT, b_proj, out, nullptr, nullptr, nullptr, M, NEMBD, NEMBD, NEMBD / 128);
}

// Round 11
// 108.905 us; speedup vs baseline: 1.2423x; 1.0731x over previous
//
#include <hip/hip_runtime.h>
#include <hip/hip_bf16.h>
#include <math.h>
#include <type_traits>

// Problem constants (CausalSelfAttention, GPT-2 small shape)
#define BATCH 8
#define SEQ   1024
#define NEMBD 768
#define NHEAD 12
#define HDIM  64
#define TC    (3 * NEMBD)   // 2304

typedef __attribute__((ext_vector_type(4))) float f32x4;
typedef __attribute__((ext_vector_type(8))) short s16x8;   // 8 bf16 in 4 VGPRs

__device__ __forceinline__ unsigned short f2bf(float f) {
    return __builtin_bit_cast(unsigned short, __float2bfloat16(f));
}

// async global->LDS, 16B per lane (dwordx4)
__device__ __forceinline__ void gload_lds16(const void* g, void* l) {
    __builtin_amdgcn_global_load_lds(
        (const __attribute__((address_space(1))) void*)g,
        (__attribute__((address_space(3))) void*)l, 16, 0, 0);
}

// ---------------------------------------------------------------------------
// cast fp32 -> bf16, 8 elements/thread
// ---------------------------------------------------------------------------
__global__ __launch_bounds__(256) void cast_bf16_kernel(
    const float* __restrict__ in, unsigned short* __restrict__ out, int n)
{
    const int i = (blockIdx.x * 256 + threadIdx.x) * 8;
    float4 a = *(const float4*)(in + i);
    float4 b = *(const float4*)(in + i + 4);
    s16x8 v;
    v[0] = f2bf(a.x); v[1] = f2bf(a.y); v[2] = f2bf(a.z); v[3] = f2bf(a.w);
    v[4] = f2bf(b.x); v[5] = f2bf(b.y); v[6] = f2bf(b.z); v[7] = f2bf(b.w);
    *(s16x8*)(out + i) = v;
}

// ---------------------------------------------------------------------------
// transpose + cast: w[K][N] fp32 -> wT[N][K] bf16. 32x32 LDS tiles.
// ---------------------------------------------------------------------------
__global__ __launch_bounds__(256) void transpose_cast_kernel(
    const float* __restrict__ w, unsigned short* __restrict__ wT, int K, int N)
{
    __shared__ float t[32][33];
    const int tx = threadIdx.x, ty = threadIdx.y;   // block (32,8)
    const int n0 = blockIdx.x * 32, k0 = blockIdx.y * 32;
    #pragma unroll
    for (int i = 0; i < 4; ++i)
        t[ty + i * 8][tx] = w[(size_t)(k0 + ty + i * 8) * N + n0 + tx];
    __syncthreads();
    #pragma unroll
    for (int i = 0; i < 4; ++i)
        wT[(size_t)(n0 + ty + i * 8) * K + k0 + tx] = f2bf(t[tx][ty + i * 8]);
}

// ---------------------------------------------------------------------------
// 3-buffer counted-vmcnt bf16 MFMA GEMM (r10 structure, unchanged except the
// Q pre-scale): C = A @ Bt^T + bias.  128x128, BK=32, 4 waves, 48KB LDS.
// OUTK=1 QKV epilogue pre-scales the Q region by 0.125*log2(e) so attention
// runs its softmax in the exp2 domain with no per-element scale mul.
// ---------------------------------------------------------------------------
template <int OUTK>
__global__ __launch_bounds__(256) void gemm_pipe3_kernel(
    const unsigned short* __restrict__ A,   // [M][K] bf16
    const unsigned short* __restrict__ Bt,  // [N][K] bf16 (= B^T)
    const float* __restrict__ bias,         // [N] fp32
    float* __restrict__ C,                  // OUTK==0
    unsigned short* __restrict__ Qb,        // OUTK==1
    unsigned short* __restrict__ Kb,
    unsigned short* __restrict__ Vtb,
    int M, int N, int K, int nbn)
{
    constexpr int BUF = 16384;                       // bytes per K-tile buffer
    __shared__ __align__(16) char SM[3 * BUF];       // 48KB

    const int tid  = threadIdx.x;
    const int w    = tid >> 6, lane = tid & 63;
    const int lr   = lane & 15, lg = lane >> 4;
    const int wr   = w >> 1, wc = w & 1;

    const int swz = (blockIdx.x & 7) * (gridDim.x >> 3) + (blockIdx.x >> 3);
    const int bm = (swz / nbn) * 128, bn = (swz % nbn) * 128;

    const int srow = tid >> 2;                       // 0..63
    const int gcol = ((tid & 3) ^ ((srow >> 1) & 3)) * 8;
    const unsigned short* Ag = A  + (size_t)(bm + srow) * K + gcol;
    const unsigned short* Bg = Bt + (size_t)(bn + srow) * K + gcol;

    const int NT = K >> 5;                           // K/32 = 24

    f32x4 acc[4][4];
    #pragma unroll
    for (int m = 0; m < 4; ++m)
        #pragma unroll
        for (int n = 0; n < 4; ++n) acc[m][n] = (f32x4){0.f, 0.f, 0.f, 0.f};

    auto stage = [&](int t) {
        const int k0 = t << 5;
        char* buf = SM + (t % 3) * BUF;
        #pragma unroll
        for (int p = 0; p < 2; ++p)
            gload_lds16(Ag + (size_t)(p * 64) * K + k0,
                        buf + p * 4096 + tid * 16);
        #pragma unroll
        for (int p = 0; p < 2; ++p)
            gload_lds16(Bg + (size_t)(p * 64) * K + k0,
                        buf + 8192 + p * 4096 + tid * 16);
    };

    stage(0);
    stage(1);
    asm volatile("s_waitcnt vmcnt(4)" ::: "memory");
    __builtin_amdgcn_sched_barrier(0);
    __builtin_amdgcn_s_barrier();
    __builtin_amdgcn_sched_barrier(0);

    for (int t = 0; t < NT; ++t) {
        const char* buf = SM + (t % 3) * BUF;
        const bool more = (t + 2 < NT);
        if (more) stage(t + 2);

        s16x8 af[4], bfr[4];
        #pragma unroll
        for (int m = 0; m < 4; ++m) {
            const int ar = wr * 64 + m * 16 + lr;
            af[m] = *(const s16x8*)(buf + ar * 64 + ((lg ^ ((ar >> 1) & 3)) * 16));
        }
        #pragma unroll
        for (int n = 0; n < 4; ++n) {
            const int br = wc * 64 + n * 16 + lr;
            bfr[n] = *(const s16x8*)(buf + 8192 + br * 64
                                         + ((lg ^ ((br >> 1) & 3)) * 16));
        }

        __builtin_amdgcn_s_setprio(1);
        #pragma unroll
        for (int m = 0; m < 4; ++m)
            #pragma unroll
            for (int n = 0; n < 4; ++n)
                acc[m][n] = __builtin_amdgcn_mfma_f32_16x16x32_bf16(
                    af[m], bfr[n], acc[m][n], 0, 0, 0);
        __builtin_amdgcn_s_setprio(0);

        if (more) asm volatile("s_waitcnt vmcnt(4)" ::: "memory");
        else      asm volatile("s_waitcnt vmcnt(0)" ::: "memory");
        __builtin_amdgcn_sched_barrier(0);
        __builtin_amdgcn_s_barrier();
        __builtin_amdgcn_sched_barrier(0);
    }

    if constexpr (OUTK == 0) {
        #pragma unroll
        for (int n = 0; n < 4; ++n) {
            const int col = bn + wc * 64 + n * 16 + lr;
            const float bv = bias[col];
            #pragma unroll
            for (int m = 0; m < 4; ++m) {
                const int row0 = bm + wr * 64 + m * 16 + lg * 4;
                #pragma unroll
                for (int r = 0; r < 4; ++r)
                    C[(size_t)(row0 + r) * N + col] = acc[m][n][r] + bv;
            }
        }
    } else {
        // ---- coalesced QKV epilogue, retile in reused buffer LDS ----
        char* Ep = SM + w * 8192;

        const int region = bn / NEMBD;               // 0=Q, 1=K, 2=V
        const int hh = ((bn % NEMBD) >> 6) + wc;     // head 0..11
        const int row0 = bm + wr * 64;               // 64-aligned
        const int bb = row0 >> 10, t0 = row0 & 1023; // no 1024-crossing
        // Q pre-scale: 0.125 (1/sqrt 64) * log2(e) -> exp2-domain softmax
        const float scl = (region == 0) ? 0.1803368801111354f : 1.0f;

        float bvn[4];
        #pragma unroll
        for (int n = 0; n < 4; ++n) bvn[n] = bias[bn + wc * 64 + n * 16 + lr];

        if (region == 2) {
            #pragma unroll
            for (int m = 0; m < 4; ++m)
                #pragma unroll
                for (int n = 0; n < 4; ++n) {
                    ushort4 pk;
                    pk.x = f2bf(acc[m][n][0] + bvn[n]);
                    pk.y = f2bf(acc[m][n][1] + bvn[n]);
                    pk.z = f2bf(acc[m][n][2] + bvn[n]);
                    pk.w = f2bf(acc[m][n][3] + bvn[n]);
                    const int row = n * 16 + lr;
                    const int lc  = m * 2 + (lg >> 1);        // logical 16B chunk
                    *(ushort4*)(Ep + row * 128 + ((lc ^ (lr & 7)) * 16)
                                   + (lg & 1) * 8) = pk;
                }
        } else {
            #pragma unroll
            for (int m = 0; m < 4; ++m)
                #pragma unroll
                for (int n = 0; n < 4; ++n)
                    #pragma unroll
                    for (int r = 0; r < 4; ++r) {
                        const int row = m * 16 + lg * 4 + r;
                        const int lc  = n * 2 + (lr >> 3);
                        *(unsigned short*)(Ep + row * 128
                            + ((lc ^ (row & 7)) * 16) + (lr & 7) * 2) =
                            f2bf((acc[m][n][r] + bvn[n]) * scl);
                    }
        }
        asm volatile("s_waitcnt lgkmcnt(0)" ::: "memory");
        __builtin_amdgcn_sched_barrier(0);

        const int rr0 = lane >> 3;   // row sub-index 0..7
        const int cc  = lane & 7;    // logical 16B chunk 0..7
        if (region == 2) {
            unsigned short* dst = Vtb + (((size_t)bb * NHEAD + hh) * HDIM) * SEQ + t0;
            #pragma unroll
            for (int it = 0; it < 8; ++it) {
                const int d = it * 8 + rr0;
                s16x8 v = *(const s16x8*)(Ep + d * 128 + ((cc ^ (d & 7)) * 16));
                *(s16x8*)(dst + (size_t)d * SEQ + cc * 8) = v;
            }
        } else {
            unsigned short* dst = (region == 0 ? Qb : Kb)
                                + ((size_t)bb * NHEAD + hh) * SEQ * HDIM;
            #pragma unroll
            for (int it = 0; it < 8; ++it) {
                const int t = it * 8 + rr0;
                s16x8 v = *(const s16x8*)(Ep + t * 128 + ((cc ^ (t & 7)) * 16));
                *(s16x8*)(dst + (size_t)(t0 + t) * HDIM + cc * 8) = v;
            }
        }
    }
}

// ---------------------------------------------------------------------------
// Flash attention, bf16 MFMA, operand-swapped (S^T) softmax, exp2 domain
// (Q pre-scaled by 0.125*log2e in the QKV GEMM), defer-max (THR=8),
// pad-72 K/V LDS (staging writes 2-way-free, reads at b128 minimum).
// Causal pair-balancing: 768 blocks; block = (xcd-class, bh, pair p) runs
// q-tile 15-p (heavy) then p (light): uniform 17 tile-iters per block, and
// 768 x 27.6KB = 3 blocks/CU -> entire grid co-resident, no tail.
// Block 256 thr = 4 waves; wave w owns 16 q-rows of the current q-tile.
// ---------------------------------------------------------------------------
__global__ __launch_bounds__(256) void attn_mfma_kernel(
    const unsigned short* __restrict__ Qb,
    const unsigned short* __restrict__ Kb,
    const unsigned short* __restrict__ Vtb,
    unsigned short* __restrict__ y)
{
    const int bid  = blockIdx.x;          // 0..767
    const int xcd  = bid & 7;
    const int grp  = bid >> 3;            // 0..95
    const int pair = grp & 7;             // 0..7
    const int bh   = xcd + 8 * (grp >> 3);// 0..95 (bh % 8 == xcd-class)
    const int b    = bh / NHEAD, h = bh % NHEAD;

    const int tid  = threadIdx.x;
    const int w    = tid >> 6;
    const int lane = tid & 63;
    const int lr   = lane & 15;
    const int lg   = lane >> 4;

    __shared__ __align__(16) unsigned short Ks[64 * 72];    // [k][d] pad-72
    __shared__ __align__(16) unsigned short Vs[64 * 72];    // [d][t] pad-72
    __shared__ __align__(16) unsigned short Ps[4][16][72];  // per-wave P [q][k]

    const unsigned short* Kg = Kb  + (size_t)bh * SEQ * HDIM;
    const unsigned short* Vg = Vtb + (size_t)bh * HDIM * SEQ;

    // staging maps: thread -> row tid>>2 (0..63), 16-elem chunk (tid&3)
    const int sr = tid >> 2;
    const int sc = (tid & 3) * 16;
    const unsigned short* Kgr = Kg + (size_t)sr * HDIM + sc;
    const unsigned short* Vgr = Vg + (size_t)sr * SEQ  + sc;
    unsigned short* KsW = Ks + sr * 72 + sc;
    unsigned short* VsW = Vs + sr * 72 + sc;

    auto process = [&](int qt) {
        const unsigned short* Qg =
            Qb + ((size_t)bh * SEQ + qt * 64 + w * 16) * HDIM;
        // Q B-frags (pre-scaled): col q = lr, d = kc*32 + lg*8 + j
        s16x8 qf[2];
        #pragma unroll
        for (int kc = 0; kc < 2; ++kc)
            qf[kc] = *(const s16x8*)(Qg + (size_t)lr * HDIM + kc * 32 + lg * 8);

        f32x4 acc[4];                     // O^T frags: row d, col q = lr
        #pragma unroll
        for (int df = 0; df < 4; ++df) acc[df] = (f32x4){0.f, 0.f, 0.f, 0.f};
        float mrow = -INFINITY, lrow = 0.f;

        const int NT   = qt + 1;
        const int qrow = qt * 64 + w * 16 + lr;

        // prologue: tile-0 loads into regs
        s16x8 krA = *(const s16x8*)(Kgr);
        s16x8 krB = *(const s16x8*)(Kgr + 8);
        s16x8 vrA = *(const s16x8*)(Vgr);
        s16x8 vrB = *(const s16x8*)(Vgr + 8);

        for (int kt = 0; kt < NT; ++kt) {
            __syncthreads();              // prior LDS reads done (both phases)
            *(s16x8*)(KsW)     = krA;
            *(s16x8*)(KsW + 8) = krB;
            *(s16x8*)(VsW)     = vrA;
            *(s16x8*)(VsW + 8) = vrB;
            __syncthreads();              // tile visible
            if (kt + 1 < NT) {            // T14: issue next tile's loads now
                krA = *(const s16x8*)(Kgr + (size_t)(kt + 1) * 64 * HDIM);
                krB = *(const s16x8*)(Kgr + (size_t)(kt + 1) * 64 * HDIM + 8);
                vrA = *(const s16x8*)(Vgr + (kt + 1) * 64);
                vrB = *(const s16x8*)(Vgr + (kt + 1) * 64 + 8);
            }

            // ---- S^T = K Q : 8 MFMA (A = K rows from LDS, B = Q) ----
            f32x4 sf[4];
            __builtin_amdgcn_s_setprio(1);
            #pragma unroll
            for (int s = 0; s < 4; ++s) {
                const unsigned short* kr = &Ks[(s * 16 + lr) * 72 + lg * 8];
                s16x8 a0 = *(const s16x8*)(kr);
                s16x8 a1 = *(const s16x8*)(kr + 32);
                sf[s] = __builtin_amdgcn_mfma_f32_16x16x32_bf16(
                    a0, qf[0], (f32x4){0.f, 0.f, 0.f, 0.f}, 0, 0, 0);
                sf[s] = __builtin_amdgcn_mfma_f32_16x16x32_bf16(a1, qf[1], sf[s], 0, 0, 0);
            }
            __builtin_amdgcn_s_setprio(0);

            // ---- causal mask (exp2-domain scores, no scale mul) ----
            float sv[4][4];
            #pragma unroll
            for (int s = 0; s < 4; ++s)
                #pragma unroll
                for (int r = 0; r < 4; ++r)
                    sv[s][r] = sf[s][r];
            if (kt == NT - 1) {
                const int kbase = kt * 64;
                #pragma unroll
                for (int s = 0; s < 4; ++s)
                    #pragma unroll
                    for (int r = 0; r < 4; ++r)
                        if (kbase + s * 16 + lg * 4 + r > qrow)
                            sv[s][r] = -INFINITY;
            }

            // ---- online softmax, exp2 domain + defer-max (THR=8) ----
            float mx4[4];
            #pragma unroll
            for (int s = 0; s < 4; ++s)
                mx4[s] = fmaxf(fmaxf(sv[s][0], sv[s][1]), fmaxf(sv[s][2], sv[s][3]));
            float mx = fmaxf(fmaxf(mx4[0], mx4[1]), fmaxf(mx4[2], mx4[3]));
            mx = fmaxf(mx, __shfl_xor(mx, 16, 64));
            mx = fmaxf(mx, __shfl_xor(mx, 32, 64));
            if (!__all(mx - mrow <= 8.f)) {      // rescale (wave-uniform)
                const float mnew = fmaxf(mrow, mx);
                const float al   = exp2f(mrow - mnew);   // -inf first tile -> 0
                lrow *= al;
                #pragma unroll
                for (int df = 0; df < 4; ++df) acc[df] *= al;
                mrow = mnew;
            }

            float rsum = 0.f;
            #pragma unroll
            for (int s = 0; s < 4; ++s) {
                float p0 = exp2f(sv[s][0] - mrow);
                float p1 = exp2f(sv[s][1] - mrow);
                float p2 = exp2f(sv[s][2] - mrow);
                float p3 = exp2f(sv[s][3] - mrow);
                rsum += (p0 + p1) + (p2 + p3);
                ushort4 pk;
                pk.x = f2bf(p0); pk.y = f2bf(p1); pk.z = f2bf(p2); pk.w = f2bf(p3);
                *(ushort4*)&Ps[w][lr][s * 16 + lg * 4] = pk;   // k-contiguous
            }
            rsum += __shfl_xor(rsum, 16, 64);
            rsum += __shfl_xor(rsum, 32, 64);
            lrow += rsum;

            asm volatile("s_waitcnt lgkmcnt(0)" ::: "memory");
            __builtin_amdgcn_sched_barrier(0);
            s16x8 pa[2];
            #pragma unroll
            for (int kc = 0; kc < 2; ++kc)
                pa[kc] = *(const s16x8*)&Ps[w][lr][kc * 32 + lg * 8];

            // ---- O^T += V^T P^T : 8 MFMA (A = V^T rows from LDS) ----
            __builtin_amdgcn_s_setprio(1);
            #pragma unroll
            for (int df = 0; df < 4; ++df) {
                const unsigned short* vr = &Vs[(df * 16 + lr) * 72 + lg * 8];
                s16x8 va0 = *(const s16x8*)(vr);
                s16x8 va1 = *(const s16x8*)(vr + 32);
                acc[df] = __builtin_amdgcn_mfma_f32_16x16x32_bf16(va0, pa[0], acc[df], 0, 0, 0);
                acc[df] = __builtin_amdgcn_mfma_f32_16x16x32_bf16(va1, pa[1], acc[df], 0, 0, 0);
            }
            __builtin_amdgcn_s_setprio(0);
        }

        // ---- epilogue: lane-local 1/l, write y (8B packed) ----
        const float inv = 1.f / lrow;
        const int t = qt * 64 + w * 16 + lr;
        unsigned short* yp = y + ((size_t)(b * SEQ) + t) * NEMBD + h * HDIM;
        #pragma unroll
        for (int df = 0; df < 4; ++df) {
            ushort4 pk;
            pk.x = f2bf(acc[df][0] * inv);
            pk.y = f2bf(acc[df][1] * inv);
            pk.z = f2bf(acc[df][2] * inv);
            pk.w = f2bf(acc[df][3] * inv);
            *(ushort4*)(yp + df * 16 + lg * 4) = pk;
        }
    };

    process(15 - pair);   // heavy q-tile first
    process(pair);        // light q-tile (pair < 8 => always distinct)
}

// ---------------------------------------------------------------------------
extern "C" void kernel_launch(void* const* d_in, const int* in_sizes, int n_in,
                              void* d_out, int out_size, void* d_ws, size_t ws_size,
                              hipStream_t stream)
{
    const float* x      = (const float*)d_in[0];
    const float* w_attn = (const float*)d_in[1];
    const float* b_attn = (const float*)d_in[2];
    const float* w_proj = (const float*)d_in[3];
    const float* b_proj = (const float*)d_in[4];
    float* out = (float*)d_out;

    const int M = BATCH * SEQ;                       // 8192
    const size_t NQKV = (size_t)M * NEMBD;           // 6.29M elements

    unsigned short* xb  = (unsigned short*)d_ws;           // [M][768]
    unsigned short* waT = xb  + NQKV;                      // [2304][768]
    unsigned short* wpT = waT + (size_t)TC * NEMBD;        // [768][768]
    unsigned short* Qb  = wpT + (size_t)NEMBD * NEMBD;     // [B][H][T][D]
    unsigned short* Kb  = Qb  + NQKV;                      // [B][H][T][D]
    unsigned short* Vtb = Kb  + NQKV;                      // [B][H][D][T]
    unsigned short* yb  = Vtb + NQKV;                      // [M][768]

    // 0) bf16 prep
    cast_bf16_kernel<<<(M * NEMBD) / 2048, 256, 0, stream>>>(x, xb, M * NEMBD);
    transpose_cast_kernel<<<dim3(TC / 32, NEMBD / 32), dim3(32, 8), 0, stream>>>(
        w_attn, waT, NEMBD, TC);
    transpose_cast_kernel<<<dim3(NEMBD / 32, NEMBD / 32), dim3(32, 8), 0, stream>>>(
        w_proj, wpT, NEMBD, NEMBD);

    // 1) fused QKV GEMM (3-buffer pipeline) -> Q(pre-scaled), K, V^T (bf16)
    gemm_pipe3_kernel<1><<<(TC / 128) * (M / 128), 256, 0, stream>>>(
        xb, waT, b_attn, nullptr, Qb, Kb, Vtb, M, TC, NEMBD, TC / 128);

    // 2) pair-balanced exp2 MFMA attention -> yb bf16 [B,T,C]
    attn_mfma_kernel<<<768, 256, 0, stream>>>(Qb, Kb, Vtb, yb);

    // 3) out(fp32) = yb @ wpT^T + b_proj (3-buffer pipeline)
    gemm_pipe3_kernel<0><<<(NEMBD / 128) * (M / 128), 256, 0, stream>>>(
        yb, wpT, b_proj, out, nullptr, nullptr, nullptr, M, NEMBD, NEMBD, NEMBD / 128);
}